// Round 1
// 1206.186 us; speedup vs baseline: 5.8353x; 5.8353x over previous
//
#include <hip/hip_runtime.h>
#include <math.h>

// StreamingDPM: probs = softmax([ -0.5*(D log2pi + logdet_k + quad_nk) + log_prior_k | log_new ])
// N=4096 D=256 K=64, out [N, K+1] fp32.
//
// ws layout (floats):
//   S : K*D*D  (sweep workspace; after sweep holds -Sigma^{-1})
//   cA: K      (log_prior_k - 0.5*(D log2pi + logdet_k))
//   lp: N*K    (log-probs before softmax, clusters only)

#define DD 256
#define KC 64
#define NPTS 4096
#define NT 64
#define BB 64          // sweep block size
#define NBS (DD / BB)  // 4 block steps

// ---------------- Kernel 1: BLOCKED in-place sweep (SPD inverse + logdet) ----
// One block (512 threads) per cluster. Blocked sweep, B=64:
//   per step: sweep 64x64 pivot block in LDS, T' = (-P^-1) * S[J,:] (LDS GEMM),
//   trailing update S_II += C*T', column block S_IJ = -C*(-P^-1).
// After all 4 steps, S_k = -Sigma_k^{-1}; logdet = sum log(pivots).
__global__ __launch_bounds__(512) void sweep_kernel(
    const float* __restrict__ covs, const float* __restrict__ counts,
    const int* __restrict__ n_points_p, float* __restrict__ S,
    float* __restrict__ cA)
{
  const int k = blockIdx.x;
  const int tid = threadIdx.x;
  float* Sk = S + (size_t)k * DD * DD;
  const float* Ck = covs + (size_t)k * DD * DD;

  __shared__ float Pl[BB][BB + 4];  // pivot block (pad keeps float4 row align)
  __shared__ float Tl[BB][DD];      // staged S[J,:], then T' = Pl * S[J,:]
  __shared__ float pivr[BB];
  __shared__ float pivc[BB];

  // copy cov -> workspace (coalesced float4)
  #pragma unroll 4
  for (int q = 0; q < 32; ++q) {
    int f = (q * 512 + tid) * 4;
    *reinterpret_cast<float4*>(Sk + f) = *reinterpret_cast<const float4*>(Ck + f);
  }

  float ld = 0.0f;  // only tid 0's value is used

  for (int bs = 0; bs < NBS; ++bs) {
    const int j0 = bs * BB;
    __syncthreads();  // prior phase's Sk writes (and initial copy) visible

    // ---- load pivot block P = S[J,J] into LDS
    #pragma unroll
    for (int q = 0; q < 8; ++q) {
      int e = q * 512 + tid;
      int r = e >> 6, c = e & 63;
      Pl[r][c] = Sk[(size_t)(j0 + r) * DD + (j0 + c)];
    }
    __syncthreads();

    // ---- sweep the 64x64 pivot block entirely in LDS -> Pl = -P^{-1}
    for (int p = 0; p < BB; ++p) {
      if (tid < BB) { pivc[tid] = Pl[tid][p]; pivr[tid] = Pl[p][tid]; }
      __syncthreads();
      const float d = pivc[p];
      const float inv_d = 1.0f / d;
      if (tid == 0) ld += logf(d);
      #pragma unroll
      for (int q = 0; q < 8; ++q) {
        int e = q * 512 + tid;
        int r = e >> 6, c = e & 63;
        float v;
        if (r == p)      v = (c == p) ? -inv_d : pivr[c] * inv_d;
        else if (c == p) v = pivc[r] * inv_d;
        else             v = fmaf(-pivc[r] * inv_d, pivr[c], Pl[r][c]);
        Pl[r][c] = v;  // element (r,c) owned by exactly one thread
      }
      __syncthreads();
    }

    // ---- stage SJ = S[J,:] into Tl (coalesced)
    #pragma unroll
    for (int q = 0; q < 8; ++q) {
      int e = (q * 512 + tid) * 4;
      int r = e >> 8, c = e & 255;
      *reinterpret_cast<float4*>(&Tl[r][c]) =
          *reinterpret_cast<const float4*>(&Sk[(size_t)(j0 + r) * DD + c]);
    }
    __syncthreads();

    // ---- T' = Pl * SJ  (in place; each thread owns one column / 32 rows)
    {
      float t[32];
      #pragma unroll
      for (int r = 0; r < 32; ++r) t[r] = 0.0f;
      const int c = tid & 255;
      const int r0 = (tid >> 8) * 32;
      for (int p = 0; p < BB; p += 4) {
        float s0 = Tl[p + 0][c], s1 = Tl[p + 1][c];
        float s2 = Tl[p + 2][c], s3 = Tl[p + 3][c];
        #pragma unroll
        for (int r = 0; r < 32; ++r) {
          float4 pv = *reinterpret_cast<const float4*>(&Pl[r0 + r][p]);
          t[r] = fmaf(pv.x, s0, fmaf(pv.y, s1, fmaf(pv.z, s2, fmaf(pv.w, s3, t[r]))));
        }
      }
      __syncthreads();  // all reads of staged SJ complete before overwrite
      #pragma unroll
      for (int r = 0; r < 32; ++r) Tl[r0 + r][c] = t[r];
    }
    __syncthreads();  // T' ready

    // ---- row updates: thread (i = tid&255) owns row i, half the columns
    const int i = tid & 255;
    const int c0 = (tid >> 8) * 128;  // column half (uniform per wave)
    const int rJ = i - j0;
    const bool isJ = (rJ >= 0) && (rJ < BB);  // uniform per wave (J is 64-aligned)

    float Crow[BB];  // C_i = S[i, J], fully unrolled -> stays in VGPRs
    if (!isJ) {
      #pragma unroll
      for (int p = 0; p < BB; p += 4) {
        float4 cv = *reinterpret_cast<const float4*>(&Sk[(size_t)i * DD + j0 + p]);
        Crow[p] = cv.x; Crow[p + 1] = cv.y; Crow[p + 2] = cv.z; Crow[p + 3] = cv.w;
      }
    }
    __syncthreads();  // everyone's Crow loaded before any J-column overwrite

    if (isJ) {
      // M[J,J] = -P^{-1} = Pl ;  M[J,I] = P^{-1} R = -T'
      for (int cc = c0; cc < c0 + 128; cc += 4) {
        float4 o;
        if (cc >= j0 && cc < j0 + BB) {
          o = *reinterpret_cast<const float4*>(&Pl[rJ][cc - j0]);
        } else {
          float4 tv = *reinterpret_cast<const float4*>(&Tl[rJ][cc]);
          o.x = -tv.x; o.y = -tv.y; o.z = -tv.z; o.w = -tv.w;
        }
        *reinterpret_cast<float4*>(&Sk[(size_t)i * DD + cc]) = o;
      }
    } else {
      // M[I,J] = C P^{-1} = -(C*Pl) ;  M[I,I] = Q + C*T'
      for (int cc = c0; cc < c0 + 128; cc += 4) {
        float4 acc;
        if (cc >= j0 && cc < j0 + BB) {
          acc.x = acc.y = acc.z = acc.w = 0.0f;
          #pragma unroll
          for (int p = 0; p < BB; ++p) {
            float4 pv = *reinterpret_cast<const float4*>(&Pl[p][cc - j0]);
            acc.x = fmaf(Crow[p], pv.x, acc.x);
            acc.y = fmaf(Crow[p], pv.y, acc.y);
            acc.z = fmaf(Crow[p], pv.z, acc.z);
            acc.w = fmaf(Crow[p], pv.w, acc.w);
          }
          acc.x = -acc.x; acc.y = -acc.y; acc.z = -acc.z; acc.w = -acc.w;
        } else {
          acc = *reinterpret_cast<const float4*>(&Sk[(size_t)i * DD + cc]);
          #pragma unroll
          for (int p = 0; p < BB; ++p) {
            float4 tv = *reinterpret_cast<const float4*>(&Tl[p][cc]);
            acc.x = fmaf(Crow[p], tv.x, acc.x);
            acc.y = fmaf(Crow[p], tv.y, acc.y);
            acc.z = fmaf(Crow[p], tv.z, acc.z);
            acc.w = fmaf(Crow[p], tv.w, acc.w);
          }
        }
        *reinterpret_cast<float4*>(&Sk[(size_t)i * DD + cc]) = acc;
      }
    }
  }

  if (tid == 0) {
    float denom = (float)(*n_points_p) + 1.0f;  // ALPHA = 1
    // D*log(2*pi) = 256 * 1.8378770664093453
    cA[k] = logf(counts[k] / denom) - 0.5f * (470.49652900079047f + ld);
  }
}

// ---------------- Kernel 2: quad[n,k] = dev^T P dev, fused logp ---------------
// Block = (n-tile of 64, cluster k). dev-tile transposed in LDS (XT[i][r]),
// P = -S streamed in 16-row LDS chunks. 4x4 register outer-product per thread.
__global__ __launch_bounds__(256) void quad_kernel(
    const float* __restrict__ X, const float* __restrict__ means,
    const float* __restrict__ S, const float* __restrict__ cA,
    float* __restrict__ lp)
{
  __shared__ float XT[DD][NT];     // 64 KB: XT[i][r] = x[n0+r][i] - mean_k[i]
  __shared__ float Plds[16][DD];   // 16 KB: P chunk; reused as reduction buffer

  const int tid = threadIdx.x;
  const int n0 = blockIdx.x * NT;
  const int k = blockIdx.y;
  const float* Sk = S + (size_t)k * DD * DD;
  const float* mk = means + (size_t)k * DD;

  // stage dev tile (coalesced global reads; LDS write conflicts are one-time)
  #pragma unroll
  for (int q = 0; q < 16; ++q) {
    int f = q * 1024 + tid * 4;
    int r = f >> 8;
    int c = f & 255;
    float4 xv = *reinterpret_cast<const float4*>(X + (size_t)(n0 + r) * DD + c);
    float4 mv = *reinterpret_cast<const float4*>(mk + c);
    XT[c + 0][r] = xv.x - mv.x;
    XT[c + 1][r] = xv.y - mv.y;
    XT[c + 2][r] = xv.z - mv.z;
    XT[c + 3][r] = xv.w - mv.w;
  }

  const int tn = tid & 15;   // n sub-tile: rows tn*4 .. +3
  const int tj = tid >> 4;   // j sub-tile within each 64-wide jc block

  float y[4][4][4];  // [jc][a][b]
  #pragma unroll
  for (int jc = 0; jc < 4; ++jc)
    #pragma unroll
    for (int a = 0; a < 4; ++a)
      #pragma unroll
      for (int b = 0; b < 4; ++b)
        y[jc][a][b] = 0.0f;

  for (int ic = 0; ic < 16; ++ic) {
    __syncthreads();  // XT ready / previous chunk consumed
    #pragma unroll
    for (int q = 0; q < 4; ++q) {
      int f = q * 1024 + tid * 4;
      int rr = f >> 8;
      int cc = f & 255;
      float4 sv = *reinterpret_cast<const float4*>(Sk + (size_t)(ic * 16 + rr) * DD + cc);
      Plds[rr][cc + 0] = -sv.x;   // P = -S
      Plds[rr][cc + 1] = -sv.y;
      Plds[rr][cc + 2] = -sv.z;
      Plds[rr][cc + 3] = -sv.w;
    }
    __syncthreads();

    #pragma unroll
    for (int il = 0; il < 16; ++il) {
      const int i = ic * 16 + il;
      float4 xv = *reinterpret_cast<const float4*>(&XT[i][tn * 4]);
      #pragma unroll
      for (int jc = 0; jc < 4; ++jc) {
        float4 pv = *reinterpret_cast<const float4*>(&Plds[il][jc * 64 + tj * 4]);
        y[jc][0][0] = fmaf(xv.x, pv.x, y[jc][0][0]);
        y[jc][0][1] = fmaf(xv.x, pv.y, y[jc][0][1]);
        y[jc][0][2] = fmaf(xv.x, pv.z, y[jc][0][2]);
        y[jc][0][3] = fmaf(xv.x, pv.w, y[jc][0][3]);
        y[jc][1][0] = fmaf(xv.y, pv.x, y[jc][1][0]);
        y[jc][1][1] = fmaf(xv.y, pv.y, y[jc][1][1]);
        y[jc][1][2] = fmaf(xv.y, pv.z, y[jc][1][2]);
        y[jc][1][3] = fmaf(xv.y, pv.w, y[jc][1][3]);
        y[jc][2][0] = fmaf(xv.z, pv.x, y[jc][2][0]);
        y[jc][2][1] = fmaf(xv.z, pv.y, y[jc][2][1]);
        y[jc][2][2] = fmaf(xv.z, pv.z, y[jc][2][2]);
        y[jc][2][3] = fmaf(xv.z, pv.w, y[jc][2][3]);
        y[jc][3][0] = fmaf(xv.w, pv.x, y[jc][3][0]);
        y[jc][3][1] = fmaf(xv.w, pv.y, y[jc][3][1]);
        y[jc][3][2] = fmaf(xv.w, pv.z, y[jc][3][2]);
        y[jc][3][3] = fmaf(xv.w, pv.w, y[jc][3][3]);
      }
    }
  }
  __syncthreads();

  // epilogue: q[n] += y[jc][a][b] * dev[n][j],  j = jc*64 + tj*4 + b
  float sacc[4] = {0.0f, 0.0f, 0.0f, 0.0f};
  #pragma unroll
  for (int jc = 0; jc < 4; ++jc) {
    #pragma unroll
    for (int b = 0; b < 4; ++b) {
      const int j = jc * 64 + tj * 4 + b;
      float4 dv = *reinterpret_cast<const float4*>(&XT[j][tn * 4]);
      sacc[0] = fmaf(y[jc][0][b], dv.x, sacc[0]);
      sacc[1] = fmaf(y[jc][1][b], dv.y, sacc[1]);
      sacc[2] = fmaf(y[jc][2][b], dv.z, sacc[2]);
      sacc[3] = fmaf(y[jc][3][b], dv.w, sacc[3]);
    }
  }

  float* qred = &Plds[0][0];  // 16*64 floats, Plds dead now
  #pragma unroll
  for (int a = 0; a < 4; ++a)
    qred[tj * 64 + tn * 4 + a] = sacc[a];
  __syncthreads();

  if (tid < 64) {
    float qv = 0.0f;
    #pragma unroll
    for (int t = 0; t < 16; ++t) qv += qred[t * 64 + tid];
    lp[(size_t)(n0 + tid) * KC + k] = fmaf(-0.5f, qv, cA[k]);
  }
}

// ---------------- Kernel 3: row softmax over K+1 = 65 entries -----------------
__global__ __launch_bounds__(64) void softmax_kernel(
    const float* __restrict__ lp, const int* __restrict__ n_points_p,
    float* __restrict__ out)
{
  const int n = blockIdx.x;
  const int l = threadIdx.x;
  const float denom = (float)(*n_points_p) + 1.0f;
  const float log_new = -logf(denom);  // log(ALPHA/denom), ALPHA=1

  float v = lp[(size_t)n * KC + l];
  float m = v;
  #pragma unroll
  for (int off = 32; off > 0; off >>= 1) m = fmaxf(m, __shfl_xor(m, off, 64));
  m = fmaxf(m, log_new);

  float e = expf(v - m);
  float s = e;
  #pragma unroll
  for (int off = 32; off > 0; off >>= 1) s += __shfl_xor(s, off, 64);
  float enew = expf(log_new - m);
  s += enew;

  out[(size_t)n * (KC + 1) + l] = e / s;
  if (l == 0) out[(size_t)n * (KC + 1) + KC] = enew / s;
}

extern "C" void kernel_launch(void* const* d_in, const int* in_sizes, int n_in,
                              void* d_out, int out_size, void* d_ws, size_t ws_size,
                              hipStream_t stream)
{
  const float* x       = (const float*)d_in[0];  // [N, D]
  const float* means   = (const float*)d_in[1];  // [K, D]
  const float* covs    = (const float*)d_in[2];  // [K, D, D]
  const float* counts  = (const float*)d_in[3];  // [K]
  const int*   n_points = (const int*)d_in[4];   // scalar

  float* S  = (float*)d_ws;                       // K*D*D
  float* cA = S + (size_t)KC * DD * DD;           // K
  float* lp = cA + 64;                            // N*K
  float* out = (float*)d_out;                     // [N, K+1]

  sweep_kernel<<<KC, 512, 0, stream>>>(covs, counts, n_points, S, cA);
  quad_kernel<<<dim3(NPTS / NT, KC), 256, 0, stream>>>(x, means, S, cA, lp);
  softmax_kernel<<<NPTS, 64, 0, stream>>>(lp, n_points, out);
}

// Round 2
// 1035.867 us; speedup vs baseline: 6.7948x; 1.1644x over previous
//
#include <hip/hip_runtime.h>
#include <math.h>

// StreamingDPM: probs = softmax([ -0.5*(D log2pi + logdet_k + quad_nk) + log_prior_k | log_new ])
// N=4096 D=256 K=64, out [N, K+1] fp32.
//
// ws layout (floats):
//   S : K*D*D  (sweep workspace; after sweep holds -Sigma^{-1})
//   cA: K      (log_prior_k - 0.5*(D log2pi + logdet_k))
//   lp: N*K    (log-probs before softmax, clusters only)
// wv (= S_k * mu_k, [K][D]) lives in the OUTPUT buffer temporarily: quad reads
// it before softmax overwrites out (stream-ordered, safe).

#define DD 256
#define KC 64
#define NPTS 4096
#define NT 64
#define BB 64          // sweep block size
#define NBS (DD / BB)  // 4 block steps
#define KG 4           // clusters per quad block
#define CH 8           // P chunk rows staged per step
#define NCH (DD / CH)  // 32 chunks

// ---------------- Kernel 1: BLOCKED in-place sweep (SPD inverse + logdet) ----
// One block (512 threads) per cluster. After all 4 steps, S_k = -Sigma_k^{-1};
// logdet = sum log(pivots).
__global__ __launch_bounds__(512) void sweep_kernel(
    const float* __restrict__ covs, const float* __restrict__ counts,
    const int* __restrict__ n_points_p, float* __restrict__ S,
    float* __restrict__ cA)
{
  const int k = blockIdx.x;
  const int tid = threadIdx.x;
  float* Sk = S + (size_t)k * DD * DD;
  const float* Ck = covs + (size_t)k * DD * DD;

  __shared__ float Pl[BB][BB + 4];  // pivot block (pad keeps float4 row align)
  __shared__ float Tl[BB][DD];      // staged S[J,:], then T' = Pl * S[J,:]
  __shared__ float pivr[BB];
  __shared__ float pivc[BB];

  // copy cov -> workspace (coalesced float4)
  #pragma unroll 4
  for (int q = 0; q < 32; ++q) {
    int f = (q * 512 + tid) * 4;
    *reinterpret_cast<float4*>(Sk + f) = *reinterpret_cast<const float4*>(Ck + f);
  }

  float ld = 0.0f;  // only tid 0's value is used

  for (int bs = 0; bs < NBS; ++bs) {
    const int j0 = bs * BB;
    __syncthreads();  // prior phase's Sk writes (and initial copy) visible

    // ---- load pivot block P = S[J,J] into LDS
    #pragma unroll
    for (int q = 0; q < 8; ++q) {
      int e = q * 512 + tid;
      int r = e >> 6, c = e & 63;
      Pl[r][c] = Sk[(size_t)(j0 + r) * DD + (j0 + c)];
    }
    __syncthreads();

    // ---- sweep the 64x64 pivot block entirely in LDS -> Pl = -P^{-1}
    for (int p = 0; p < BB; ++p) {
      if (tid < BB) { pivc[tid] = Pl[tid][p]; pivr[tid] = Pl[p][tid]; }
      __syncthreads();
      const float d = pivc[p];
      const float inv_d = 1.0f / d;
      if (tid == 0) ld += logf(d);
      #pragma unroll
      for (int q = 0; q < 8; ++q) {
        int e = q * 512 + tid;
        int r = e >> 6, c = e & 63;
        float v;
        if (r == p)      v = (c == p) ? -inv_d : pivr[c] * inv_d;
        else if (c == p) v = pivc[r] * inv_d;
        else             v = fmaf(-pivc[r] * inv_d, pivr[c], Pl[r][c]);
        Pl[r][c] = v;  // element (r,c) owned by exactly one thread
      }
      __syncthreads();
    }

    // ---- stage SJ = S[J,:] into Tl (coalesced)
    #pragma unroll
    for (int q = 0; q < 8; ++q) {
      int e = (q * 512 + tid) * 4;
      int r = e >> 8, c = e & 255;
      *reinterpret_cast<float4*>(&Tl[r][c]) =
          *reinterpret_cast<const float4*>(&Sk[(size_t)(j0 + r) * DD + c]);
    }
    __syncthreads();

    // ---- T' = Pl * SJ  (in place; each thread owns one column / 32 rows)
    {
      float t[32];
      #pragma unroll
      for (int r = 0; r < 32; ++r) t[r] = 0.0f;
      const int c = tid & 255;
      const int r0 = (tid >> 8) * 32;
      for (int p = 0; p < BB; p += 4) {
        float s0 = Tl[p + 0][c], s1 = Tl[p + 1][c];
        float s2 = Tl[p + 2][c], s3 = Tl[p + 3][c];
        #pragma unroll
        for (int r = 0; r < 32; ++r) {
          float4 pv = *reinterpret_cast<const float4*>(&Pl[r0 + r][p]);
          t[r] = fmaf(pv.x, s0, fmaf(pv.y, s1, fmaf(pv.z, s2, fmaf(pv.w, s3, t[r]))));
        }
      }
      __syncthreads();  // all reads of staged SJ complete before overwrite
      #pragma unroll
      for (int r = 0; r < 32; ++r) Tl[r0 + r][c] = t[r];
    }
    __syncthreads();  // T' ready

    // ---- row updates: thread (i = tid&255) owns row i, half the columns
    const int i = tid & 255;
    const int c0 = (tid >> 8) * 128;  // column half (uniform per wave)
    const int rJ = i - j0;
    const bool isJ = (rJ >= 0) && (rJ < BB);  // uniform per wave (J is 64-aligned)

    float Crow[BB];  // C_i = S[i, J], fully unrolled -> stays in VGPRs
    if (!isJ) {
      #pragma unroll
      for (int p = 0; p < BB; p += 4) {
        float4 cv = *reinterpret_cast<const float4*>(&Sk[(size_t)i * DD + j0 + p]);
        Crow[p] = cv.x; Crow[p + 1] = cv.y; Crow[p + 2] = cv.z; Crow[p + 3] = cv.w;
      }
    }
    __syncthreads();  // everyone's Crow loaded before any J-column overwrite

    if (isJ) {
      // M[J,J] = -P^{-1} = Pl ;  M[J,I] = P^{-1} R = -T'
      for (int cc = c0; cc < c0 + 128; cc += 4) {
        float4 o;
        if (cc >= j0 && cc < j0 + BB) {
          o = *reinterpret_cast<const float4*>(&Pl[rJ][cc - j0]);
        } else {
          float4 tv = *reinterpret_cast<const float4*>(&Tl[rJ][cc]);
          o.x = -tv.x; o.y = -tv.y; o.z = -tv.z; o.w = -tv.w;
        }
        *reinterpret_cast<float4*>(&Sk[(size_t)i * DD + cc]) = o;
      }
    } else {
      // M[I,J] = C P^{-1} = -(C*Pl) ;  M[I,I] = Q + C*T'
      for (int cc = c0; cc < c0 + 128; cc += 4) {
        float4 acc;
        if (cc >= j0 && cc < j0 + BB) {
          acc.x = acc.y = acc.z = acc.w = 0.0f;
          #pragma unroll
          for (int p = 0; p < BB; ++p) {
            float4 pv = *reinterpret_cast<const float4*>(&Pl[p][cc - j0]);
            acc.x = fmaf(Crow[p], pv.x, acc.x);
            acc.y = fmaf(Crow[p], pv.y, acc.y);
            acc.z = fmaf(Crow[p], pv.z, acc.z);
            acc.w = fmaf(Crow[p], pv.w, acc.w);
          }
          acc.x = -acc.x; acc.y = -acc.y; acc.z = -acc.z; acc.w = -acc.w;
        } else {
          acc = *reinterpret_cast<const float4*>(&Sk[(size_t)i * DD + cc]);
          #pragma unroll
          for (int p = 0; p < BB; ++p) {
            float4 tv = *reinterpret_cast<const float4*>(&Tl[p][cc]);
            acc.x = fmaf(Crow[p], tv.x, acc.x);
            acc.y = fmaf(Crow[p], tv.y, acc.y);
            acc.z = fmaf(Crow[p], tv.z, acc.z);
            acc.w = fmaf(Crow[p], tv.w, acc.w);
          }
        }
        *reinterpret_cast<float4*>(&Sk[(size_t)i * DD + cc]) = acc;
      }
    }
  }

  if (tid == 0) {
    float denom = (float)(*n_points_p) + 1.0f;  // ALPHA = 1
    // D*log(2*pi) = 256 * 1.8378770664093453
    cA[k] = logf(counts[k] / denom) - 0.5f * (470.49652900079047f + ld);
  }
}

// ---------------- Kernel 1b: wv_k = S_k * mu_k (S symmetric, unnegated) ------
__global__ __launch_bounds__(256) void w_kernel(
    const float* __restrict__ S, const float* __restrict__ means,
    float* __restrict__ wv)
{
  const int k = blockIdx.x;
  const int tid = threadIdx.x;
  const float* Sk = S + (size_t)k * DD * DD;
  __shared__ float mus[DD];
  mus[tid] = means[(size_t)k * DD + tid];
  __syncthreads();
  float a0 = 0.f, a1 = 0.f, a2 = 0.f, a3 = 0.f;
  for (int j = 0; j < DD; j += 4) {
    a0 = fmaf(Sk[(size_t)(j + 0) * DD + tid], mus[j + 0], a0);
    a1 = fmaf(Sk[(size_t)(j + 1) * DD + tid], mus[j + 1], a1);
    a2 = fmaf(Sk[(size_t)(j + 2) * DD + tid], mus[j + 2], a2);
    a3 = fmaf(Sk[(size_t)(j + 3) * DD + tid], mus[j + 3], a3);
  }
  wv[(size_t)k * DD + tid] = (a0 + a1) + (a2 + a3);
}

// ---------------- Kernel 2: quad via mean-folded GEMM ------------------------
// dev^T S dev = sum_j (x_j - mu_j) * ((X*S)_nj - wv_j)   (S symmetric).
// X-tile (64 points) is k-independent -> staged once, KG=4 clusters per block.
// S_k streamed in 8-row chunks, register-prefetched (loads in flight across
// the compute phase). XT point-index XOR-swizzled to break the 64-way bank
// conflict on staging writes. LDS = 64+8+2 = 74 KB -> 2 blocks/CU.
__global__ __launch_bounds__(256, 2) void quad_kernel(
    const float* __restrict__ X, const float* __restrict__ means,
    const float* __restrict__ S, const float* __restrict__ cA,
    const float* __restrict__ wv, float* __restrict__ lp)
{
  __shared__ float XT[DD][NT];   // (i,r) stored at XT[i][r ^ (((i>>2)&15)<<2)]
  __shared__ float Pl[CH][DD];   // S chunk; reused as reduction buffer
  __shared__ float muw[2][DD];   // mu_k, wv_k

  const int tid = threadIdx.x;
  const int n0 = blockIdx.x * NT;
  const int k0 = blockIdx.y * KG;

  // stage X tile transposed + swizzled (once per block)
  #pragma unroll
  for (int q = 0; q < 16; ++q) {
    int f = q * 1024 + tid * 4;
    int r = f >> 8;
    int c = f & 255;
    float4 xv = *reinterpret_cast<const float4*>(X + (size_t)(n0 + r) * DD + c);
    int rs = r ^ (((c >> 2) & 15) << 2);
    XT[c + 0][rs] = xv.x;
    XT[c + 1][rs] = xv.y;
    XT[c + 2][rs] = xv.z;
    XT[c + 3][rs] = xv.w;
  }

  const int tn = tid & 15;   // n sub-tile: rows tn*4 .. +3
  const int tj = tid >> 4;   // j sub-tile within each 64-wide jc block
  const int f0 = tid * 4;
  const int f1 = 1024 + tid * 4;

  #pragma unroll 1
  for (int kk = 0; kk < KG; ++kk) {
    const int k = k0 + kk;
    const float* Sk = S + (size_t)k * DD * DD;

    __syncthreads();  // prev k's qred readers done; XT staged (kk==0)
    muw[0][tid] = means[(size_t)k * DD + tid];
    muw[1][tid] = wv[(size_t)k * DD + tid];

    // prologue: chunk 0 -> registers
    float4 pre0 = *reinterpret_cast<const float4*>(Sk + (size_t)(f0 >> 8) * DD + (f0 & 255));
    float4 pre1 = *reinterpret_cast<const float4*>(Sk + (size_t)(f1 >> 8) * DD + (f1 & 255));

    float y[4][4][4];  // [jc][a][b]
    #pragma unroll
    for (int jc = 0; jc < 4; ++jc)
      #pragma unroll
      for (int a = 0; a < 4; ++a)
        #pragma unroll
        for (int b = 0; b < 4; ++b)
          y[jc][a][b] = 0.0f;

    #pragma unroll 1
    for (int ct = 0; ct < NCH; ++ct) {
      __syncthreads();  // Pl free (prev chunk consumed); muw/XT visible
      *reinterpret_cast<float4*>(&Pl[f0 >> 8][f0 & 255]) = pre0;
      *reinterpret_cast<float4*>(&Pl[f1 >> 8][f1 & 255]) = pre1;
      if (ct < NCH - 1) {  // issue next chunk's loads; in flight across compute
        const float* src = Sk + (size_t)(ct + 1) * CH * DD;
        pre0 = *reinterpret_cast<const float4*>(src + (size_t)(f0 >> 8) * DD + (f0 & 255));
        pre1 = *reinterpret_cast<const float4*>(src + (size_t)(f1 >> 8) * DD + (f1 & 255));
      }
      __syncthreads();  // Pl ready

      #pragma unroll
      for (int il = 0; il < CH; ++il) {
        const int i = ct * CH + il;
        const int sw = ((i >> 2) & 15) << 2;
        float4 xv = *reinterpret_cast<const float4*>(&XT[i][(tn * 4) ^ sw]);
        #pragma unroll
        for (int jc = 0; jc < 4; ++jc) {
          float4 pv = *reinterpret_cast<const float4*>(&Pl[il][jc * 64 + tj * 4]);
          y[jc][0][0] = fmaf(xv.x, pv.x, y[jc][0][0]);
          y[jc][0][1] = fmaf(xv.x, pv.y, y[jc][0][1]);
          y[jc][0][2] = fmaf(xv.x, pv.z, y[jc][0][2]);
          y[jc][0][3] = fmaf(xv.x, pv.w, y[jc][0][3]);
          y[jc][1][0] = fmaf(xv.y, pv.x, y[jc][1][0]);
          y[jc][1][1] = fmaf(xv.y, pv.y, y[jc][1][1]);
          y[jc][1][2] = fmaf(xv.y, pv.z, y[jc][1][2]);
          y[jc][1][3] = fmaf(xv.y, pv.w, y[jc][1][3]);
          y[jc][2][0] = fmaf(xv.z, pv.x, y[jc][2][0]);
          y[jc][2][1] = fmaf(xv.z, pv.y, y[jc][2][1]);
          y[jc][2][2] = fmaf(xv.z, pv.z, y[jc][2][2]);
          y[jc][2][3] = fmaf(xv.z, pv.w, y[jc][2][3]);
          y[jc][3][0] = fmaf(xv.w, pv.x, y[jc][3][0]);
          y[jc][3][1] = fmaf(xv.w, pv.y, y[jc][3][1]);
          y[jc][3][2] = fmaf(xv.w, pv.z, y[jc][3][2]);
          y[jc][3][3] = fmaf(xv.w, pv.w, y[jc][3][3]);
        }
      }
    }
    __syncthreads();  // all threads done reading Pl before qred reuse

    // epilogue: q'[n] = sum_j (x[n,j]-mu_j) * (y[n,j]-wv_j)
    float sacc[4] = {0.0f, 0.0f, 0.0f, 0.0f};
    const int colbase = (tn * 4) ^ (tj << 2);  // swizzle for rows j: sw_j == tj<<2
    #pragma unroll
    for (int jc = 0; jc < 4; ++jc) {
      #pragma unroll
      for (int b = 0; b < 4; ++b) {
        const int j = jc * 64 + tj * 4 + b;
        float4 dv = *reinterpret_cast<const float4*>(&XT[j][colbase]);
        const float mj = muw[0][j];
        const float wj = muw[1][j];
        sacc[0] = fmaf(dv.x - mj, y[jc][0][b] - wj, sacc[0]);
        sacc[1] = fmaf(dv.y - mj, y[jc][1][b] - wj, sacc[1]);
        sacc[2] = fmaf(dv.z - mj, y[jc][2][b] - wj, sacc[2]);
        sacc[3] = fmaf(dv.w - mj, y[jc][3][b] - wj, sacc[3]);
      }
    }

    float* qred = &Pl[0][0];  // 2048 floats, Pl dead now
    #pragma unroll
    for (int a = 0; a < 4; ++a)
      qred[tj * 64 + tn * 4 + a] = sacc[a];
    __syncthreads();

    if (tid < 64) {
      float qv = 0.0f;
      #pragma unroll
      for (int t = 0; t < 16; ++t) qv += qred[t * 64 + tid];
      // q' = dev^T S dev = -quad  ->  lp = cA + 0.5*q'
      lp[(size_t)(n0 + tid) * KC + k] = fmaf(0.5f, qv, cA[k]);
    }
  }
}

// ---------------- Kernel 3: row softmax over K+1 = 65 entries -----------------
__global__ __launch_bounds__(64) void softmax_kernel(
    const float* __restrict__ lp, const int* __restrict__ n_points_p,
    float* __restrict__ out)
{
  const int n = blockIdx.x;
  const int l = threadIdx.x;
  const float denom = (float)(*n_points_p) + 1.0f;
  const float log_new = -logf(denom);  // log(ALPHA/denom), ALPHA=1

  float v = lp[(size_t)n * KC + l];
  float m = v;
  #pragma unroll
  for (int off = 32; off > 0; off >>= 1) m = fmaxf(m, __shfl_xor(m, off, 64));
  m = fmaxf(m, log_new);

  float e = expf(v - m);
  float s = e;
  #pragma unroll
  for (int off = 32; off > 0; off >>= 1) s += __shfl_xor(s, off, 64);
  float enew = expf(log_new - m);
  s += enew;

  out[(size_t)n * (KC + 1) + l] = e / s;
  if (l == 0) out[(size_t)n * (KC + 1) + KC] = enew / s;
}

extern "C" void kernel_launch(void* const* d_in, const int* in_sizes, int n_in,
                              void* d_out, int out_size, void* d_ws, size_t ws_size,
                              hipStream_t stream)
{
  const float* x       = (const float*)d_in[0];  // [N, D]
  const float* means   = (const float*)d_in[1];  // [K, D]
  const float* covs    = (const float*)d_in[2];  // [K, D, D]
  const float* counts  = (const float*)d_in[3];  // [K]
  const int*   n_points = (const int*)d_in[4];   // scalar

  float* S  = (float*)d_ws;                       // K*D*D
  float* cA = S + (size_t)KC * DD * DD;           // K
  float* lp = cA + 64;                            // N*K
  float* out = (float*)d_out;                     // [N, K+1]
  // wv = S_k*mu_k staged in the out buffer (64KB of 1MB); quad reads it before
  // softmax overwrites out — kernels are stream-ordered, so this is safe.
  float* wv = out;

  sweep_kernel<<<KC, 512, 0, stream>>>(covs, counts, n_points, S, cA);
  w_kernel<<<KC, 256, 0, stream>>>(S, means, wv);
  quad_kernel<<<dim3(NPTS / NT, KC / KG), 256, 0, stream>>>(x, means, S, cA, wv, lp);
  softmax_kernel<<<NPTS, 64, 0, stream>>>(lp, n_points, out);
}

// Round 3
// 983.881 us; speedup vs baseline: 7.1538x; 1.0528x over previous
//
#include <hip/hip_runtime.h>
#include <math.h>

// StreamingDPM: probs = softmax([ -0.5*(D log2pi + logdet_k + quad_nk) + log_prior_k | log_new ])
// N=4096 D=256 K=64, out [N, K+1] fp32.
//
// ws layout (floats):
//   S    : K*D*D  (sweep result; holds -Sigma^{-1} after all steps)
//   cA   : K      (log_prior_k - 0.5*(D log2pi + logdet_k))
//   ldp  : 4*K    (per-block-step logdet partials)
//   lp   : N*K    (log-probs before softmax; ALIASED as Plbuf during sweep)
// wv (= S_k * mu_k, [K][D]) lives in the OUTPUT buffer temporarily (quad reads
// it before softmax overwrites out; stream-ordered, safe).
//
// Sweep is split into per-block-step launches for full-chip parallelism:
//   for bs in 0..3:  pivot_kernel(bs)  [64 blocks]  — deferred J-col write of
//                      step bs-1, then sweep P_bs in LDS -> Plbuf, logdet part
//                    update_kernel(bs) [64x3 blocks] — T' = Pl*S[J,slice] and
//                      trailing update on the 3 non-J column slices
//   pivot_kernel(4) — flush J_3 columns + assemble cA.
// J-column writes are deferred one launch so no block ever writes S[:,J] while
// another reads it (C = S[:,J] is read by all update blocks). Step 0 reads covs
// directly (no copy kernel; covs never written).

#define DD 256
#define KC 64
#define NPTS 4096
#define NT 64
#define BB 64          // sweep block size
#define KG 4           // clusters per quad block
#define CH 16          // S chunk rows staged per quad step
#define NCH (DD / CH)  // 16 chunks

// ---------------- Kernel 1a: pivot-block sweep (+ deferred J-col writeback) --
__global__ __launch_bounds__(512) void pivot_kernel(
    const float* __restrict__ covs, const float* __restrict__ counts,
    const int* __restrict__ n_points_p, float* __restrict__ S,
    float* __restrict__ Plbuf, float* __restrict__ ldp, float* __restrict__ cA,
    int bs)
{
  const int k = blockIdx.x;
  const int tid = threadIdx.x;
  __shared__ float Pl[BB][BB + 4];
  __shared__ float pivr[BB];
  __shared__ float pivc[BB];
  float* Pb = Plbuf + (size_t)k * BB * BB;

  if (bs > 0) {
    // ---- deferred write of step bs-1's J columns:
    //  M[J,J] = -P^{-1} = Pl_prev ;  M[I,J] = C*P^{-1} = -(C*Pl_prev)
    const int j0p = (bs - 1) * BB;
    const float* src = ((bs == 1) ? covs : (const float*)S) + (size_t)k * DD * DD;
    float* dstm = S + (size_t)k * DD * DD;
    #pragma unroll
    for (int q = 0; q < 8; ++q) {
      int e = q * 512 + tid;
      Pl[e >> 6][e & 63] = Pb[e];
    }
    __syncthreads();
    const int r = tid & 255;
    const int h = (tid >> 8) * 32;
    const bool inJ = (r >= j0p) && (r < j0p + BB);  // wave-uniform (64-aligned)
    if (inJ) {
      #pragma unroll
      for (int c = 0; c < 32; c += 4) {
        *reinterpret_cast<float4*>(&dstm[(size_t)r * DD + j0p + h + c]) =
            *reinterpret_cast<const float4*>(&Pl[r - j0p][h + c]);
      }
    } else {
      float Crow[BB];
      #pragma unroll
      for (int p = 0; p < BB; p += 4) {
        float4 cv = *reinterpret_cast<const float4*>(&src[(size_t)r * DD + j0p + p]);
        Crow[p] = cv.x; Crow[p + 1] = cv.y; Crow[p + 2] = cv.z; Crow[p + 3] = cv.w;
      }
      #pragma unroll
      for (int c = 0; c < 32; c += 4) {
        float ax = 0.f, ay = 0.f, az = 0.f, aw = 0.f;
        #pragma unroll
        for (int p = 0; p < BB; ++p) {
          float4 pv = *reinterpret_cast<const float4*>(&Pl[p][h + c]);
          ax = fmaf(Crow[p], pv.x, ax);
          ay = fmaf(Crow[p], pv.y, ay);
          az = fmaf(Crow[p], pv.z, az);
          aw = fmaf(Crow[p], pv.w, aw);
        }
        float4 o = {-ax, -ay, -az, -aw};
        *reinterpret_cast<float4*>(&dstm[(size_t)r * DD + j0p + h + c]) = o;
      }
    }
    __syncthreads();  // Pl about to be reused
  }

  if (bs == 4) {  // final flush: assemble cA
    if (tid == 0) {
      float denom = (float)(*n_points_p) + 1.0f;  // ALPHA = 1
      float ld = ldp[k] + ldp[KC + k] + ldp[2 * KC + k] + ldp[3 * KC + k];
      // D*log(2*pi) = 256 * 1.8378770664093453
      cA[k] = logf(counts[k] / denom) - 0.5f * (470.49652900079047f + ld);
    }
    return;
  }

  // ---- load pivot block P = S[J,J] (step 0: from covs) and sweep in LDS
  const int j0 = bs * BB;
  const float* psrc = ((bs == 0) ? covs : (const float*)S) + (size_t)k * DD * DD;
  #pragma unroll
  for (int q = 0; q < 8; ++q) {
    int e = q * 512 + tid;
    Pl[e >> 6][e & 63] = psrc[(size_t)(j0 + (e >> 6)) * DD + j0 + (e & 63)];
  }
  __syncthreads();

  float ld = 0.0f;
  for (int p = 0; p < BB; ++p) {
    if (tid < BB) { pivc[tid] = Pl[tid][p]; pivr[tid] = Pl[p][tid]; }
    __syncthreads();
    const float d = pivc[p];
    const float inv_d = 1.0f / d;
    if (tid == 0) ld += logf(d);
    #pragma unroll
    for (int q = 0; q < 8; ++q) {
      int e = q * 512 + tid;
      int r = e >> 6, c = e & 63;
      float v;
      if (r == p)      v = (c == p) ? -inv_d : pivr[c] * inv_d;
      else if (c == p) v = pivc[r] * inv_d;
      else             v = fmaf(-pivc[r] * inv_d, pivr[c], Pl[r][c]);
      Pl[r][c] = v;  // element (r,c) owned by exactly one thread
    }
    __syncthreads();
  }

  // ---- store Pl = -P^{-1} for the update/deferred kernels
  #pragma unroll
  for (int q = 0; q < 8; ++q) {
    int e = q * 512 + tid;
    Pb[e] = Pl[e >> 6][e & 63];
  }
  if (tid == 0) ldp[bs * KC + k] = ld;
}

// ---------------- Kernel 1b: trailing update of one non-J column slice ------
// Block (k, si): slice t = si + (si>=bs), columns [t*64, t*64+64).
//   T'[:,slice] = Pl * S[J, slice]  (LDS GEMM)
//   rows in J:   M[J, slice] = -T'
//   rows not J:  M[I, slice] = Q + C*T'   with C = S[:,J] (untouched this step)
__global__ __launch_bounds__(512) void update_kernel(
    const float* __restrict__ covs, float* __restrict__ S,
    const float* __restrict__ Plbuf, int bs)
{
  const int k = blockIdx.x;
  const int si = blockIdx.y;
  const int t = si + (si >= bs ? 1 : 0);
  const int c0 = t * BB;
  const int j0 = bs * BB;
  const int tid = threadIdx.x;
  const float* src = ((bs == 0) ? covs : (const float*)S) + (size_t)k * DD * DD;
  float* dst = S + (size_t)k * DD * DD;

  __shared__ float Pl[BB][BB + 4];
  __shared__ float SJ[BB][BB + 4];
  __shared__ float Tl[BB][BB + 4];

  const float* Pb = Plbuf + (size_t)k * BB * BB;
  #pragma unroll
  for (int q = 0; q < 8; ++q) {
    int e = q * 512 + tid;
    int r = e >> 6, c = e & 63;
    Pl[r][c] = Pb[e];
    SJ[r][c] = src[(size_t)(j0 + r) * DD + c0 + c];
  }
  __syncthreads();

  // ---- T' = Pl * SJ  (thread: col c, 8 rows)
  {
    const int c = tid & 63;
    const int rg = (tid >> 6) * 8;
    float tv[8];
    #pragma unroll
    for (int r = 0; r < 8; ++r) tv[r] = 0.0f;
    for (int p = 0; p < BB; p += 4) {
      float s0 = SJ[p][c], s1 = SJ[p + 1][c], s2 = SJ[p + 2][c], s3 = SJ[p + 3][c];
      #pragma unroll
      for (int r = 0; r < 8; ++r) {
        float4 pv = *reinterpret_cast<const float4*>(&Pl[rg + r][p]);
        tv[r] = fmaf(pv.x, s0, fmaf(pv.y, s1, fmaf(pv.z, s2, fmaf(pv.w, s3, tv[r]))));
      }
    }
    #pragma unroll
    for (int r = 0; r < 8; ++r) Tl[rg + r][c] = tv[r];
  }
  __syncthreads();

  // ---- apply to this column slice (thread: row r, 32 cols)
  const int r = tid & 255;
  const int h = (tid >> 8) * 32;
  const bool inJ = (r >= j0) && (r < j0 + BB);  // wave-uniform
  if (inJ) {
    #pragma unroll
    for (int c = 0; c < 32; c += 4) {
      float4 tv4 = *reinterpret_cast<const float4*>(&Tl[r - j0][h + c]);
      float4 o = {-tv4.x, -tv4.y, -tv4.z, -tv4.w};
      *reinterpret_cast<float4*>(&dst[(size_t)r * DD + c0 + h + c]) = o;
    }
  } else {
    float Crow[BB];
    #pragma unroll
    for (int p = 0; p < BB; p += 4) {
      float4 cv = *reinterpret_cast<const float4*>(&src[(size_t)r * DD + j0 + p]);
      Crow[p] = cv.x; Crow[p + 1] = cv.y; Crow[p + 2] = cv.z; Crow[p + 3] = cv.w;
    }
    #pragma unroll
    for (int c = 0; c < 32; c += 4) {
      float4 acc = *reinterpret_cast<const float4*>(&src[(size_t)r * DD + c0 + h + c]);
      #pragma unroll
      for (int p = 0; p < BB; ++p) {
        float4 tv4 = *reinterpret_cast<const float4*>(&Tl[p][h + c]);
        acc.x = fmaf(Crow[p], tv4.x, acc.x);
        acc.y = fmaf(Crow[p], tv4.y, acc.y);
        acc.z = fmaf(Crow[p], tv4.z, acc.z);
        acc.w = fmaf(Crow[p], tv4.w, acc.w);
      }
      *reinterpret_cast<float4*>(&dst[(size_t)r * DD + c0 + h + c]) = acc;
    }
  }
}

// ---------------- Kernel 1c: wv_k = S_k * mu_k -------------------------------
__global__ __launch_bounds__(256) void w_kernel(
    const float* __restrict__ S, const float* __restrict__ means,
    float* __restrict__ wv)
{
  const int k = blockIdx.x;
  const int tid = threadIdx.x;
  const float* Sk = S + (size_t)k * DD * DD;
  __shared__ float mus[DD];
  mus[tid] = means[(size_t)k * DD + tid];
  __syncthreads();
  float a0 = 0.f, a1 = 0.f, a2 = 0.f, a3 = 0.f;
  for (int j = 0; j < DD; j += 4) {
    a0 = fmaf(Sk[(size_t)(j + 0) * DD + tid], mus[j + 0], a0);
    a1 = fmaf(Sk[(size_t)(j + 1) * DD + tid], mus[j + 1], a1);
    a2 = fmaf(Sk[(size_t)(j + 2) * DD + tid], mus[j + 2], a2);
    a3 = fmaf(Sk[(size_t)(j + 3) * DD + tid], mus[j + 3], a3);
  }
  wv[(size_t)k * DD + tid] = (a0 + a1) + (a2 + a3);
}

// ---------------- Kernel 2: quad via mean-folded GEMM ------------------------
// dev^T S dev = sum_j (x_j - mu_j) * ((X*S)_nj - wv_j)   (S symmetric).
// X-tile (64 points) is k-independent -> staged once, KG=4 clusters per block.
// S_k streamed in CH=16-row chunks, register-prefetched. XT point-index
// XOR-swizzled. LDS = 64+16 = 80 KB -> 2 blocks/CU.
__global__ __launch_bounds__(256, 2) void quad_kernel(
    const float* __restrict__ X, const float* __restrict__ means,
    const float* __restrict__ S, const float* __restrict__ cA,
    const float* __restrict__ wv, float* __restrict__ lp)
{
  __shared__ float XT[DD][NT];   // (i,r) stored at XT[i][r ^ (((i>>2)&15)<<2)]
  __shared__ float Pl[CH][DD];   // S chunk; reused as reduction buffer

  const int tid = threadIdx.x;
  const int n0 = blockIdx.x * NT;
  const int k0 = blockIdx.y * KG;

  // stage X tile transposed + swizzled (once per block)
  #pragma unroll
  for (int q = 0; q < 16; ++q) {
    int f = q * 1024 + tid * 4;
    int r = f >> 8;
    int c = f & 255;
    float4 xv = *reinterpret_cast<const float4*>(X + (size_t)(n0 + r) * DD + c);
    int rs = r ^ (((c >> 2) & 15) << 2);
    XT[c + 0][rs] = xv.x;
    XT[c + 1][rs] = xv.y;
    XT[c + 2][rs] = xv.z;
    XT[c + 3][rs] = xv.w;
  }

  const int tn = tid & 15;   // n sub-tile: rows tn*4 .. +3
  const int tj = tid >> 4;   // j sub-tile within each 64-wide jc block

  #pragma unroll 1
  for (int kk = 0; kk < KG; ++kk) {
    const int k = k0 + kk;
    const float* Sk = S + (size_t)k * DD * DD;

    // prologue: chunk 0 -> registers
    float4 pre[4];
    #pragma unroll
    for (int q = 0; q < 4; ++q)
      pre[q] = *reinterpret_cast<const float4*>(Sk + q * 1024 + tid * 4);

    float y[4][4][4];  // [jc][a][b]
    #pragma unroll
    for (int jc = 0; jc < 4; ++jc)
      #pragma unroll
      for (int a = 0; a < 4; ++a)
        #pragma unroll
        for (int b = 0; b < 4; ++b)
          y[jc][a][b] = 0.0f;

    #pragma unroll 1
    for (int ct = 0; ct < NCH; ++ct) {
      __syncthreads();  // Pl free (prev chunk / prev k consumed); XT staged
      #pragma unroll
      for (int q = 0; q < 4; ++q) {
        int f = q * 1024 + tid * 4;
        *reinterpret_cast<float4*>(&Pl[f >> 8][f & 255]) = pre[q];
      }
      if (ct < NCH - 1) {  // issue next chunk's loads; in flight across compute
        const float* srcp = Sk + (size_t)(ct + 1) * CH * DD;
        #pragma unroll
        for (int q = 0; q < 4; ++q)
          pre[q] = *reinterpret_cast<const float4*>(srcp + q * 1024 + tid * 4);
      }
      __syncthreads();  // Pl ready

      #pragma unroll
      for (int il = 0; il < CH; ++il) {
        const int i = ct * CH + il;
        const int sw = ((i >> 2) & 15) << 2;
        float4 xv = *reinterpret_cast<const float4*>(&XT[i][(tn * 4) ^ sw]);
        #pragma unroll
        for (int jc = 0; jc < 4; ++jc) {
          float4 pv = *reinterpret_cast<const float4*>(&Pl[il][jc * 64 + tj * 4]);
          y[jc][0][0] = fmaf(xv.x, pv.x, y[jc][0][0]);
          y[jc][0][1] = fmaf(xv.x, pv.y, y[jc][0][1]);
          y[jc][0][2] = fmaf(xv.x, pv.z, y[jc][0][2]);
          y[jc][0][3] = fmaf(xv.x, pv.w, y[jc][0][3]);
          y[jc][1][0] = fmaf(xv.y, pv.x, y[jc][1][0]);
          y[jc][1][1] = fmaf(xv.y, pv.y, y[jc][1][1]);
          y[jc][1][2] = fmaf(xv.y, pv.z, y[jc][1][2]);
          y[jc][1][3] = fmaf(xv.y, pv.w, y[jc][1][3]);
          y[jc][2][0] = fmaf(xv.z, pv.x, y[jc][2][0]);
          y[jc][2][1] = fmaf(xv.z, pv.y, y[jc][2][1]);
          y[jc][2][2] = fmaf(xv.z, pv.z, y[jc][2][2]);
          y[jc][2][3] = fmaf(xv.z, pv.w, y[jc][2][3]);
          y[jc][3][0] = fmaf(xv.w, pv.x, y[jc][3][0]);
          y[jc][3][1] = fmaf(xv.w, pv.y, y[jc][3][1]);
          y[jc][3][2] = fmaf(xv.w, pv.z, y[jc][3][2]);
          y[jc][3][3] = fmaf(xv.w, pv.w, y[jc][3][3]);
        }
      }
    }
    __syncthreads();  // all threads done reading Pl before qred reuse

    // epilogue: q'[n] = sum_j (x[n,j]-mu_j) * (y[n,j]-wv_j)
    float sacc[4] = {0.0f, 0.0f, 0.0f, 0.0f};
    const int colbase = (tn * 4) ^ (tj << 2);  // swizzle for rows j: sw_j == tj<<2
    #pragma unroll
    for (int jc = 0; jc < 4; ++jc) {
      #pragma unroll
      for (int b = 0; b < 4; ++b) {
        const int j = jc * 64 + tj * 4 + b;
        float4 dv = *reinterpret_cast<const float4*>(&XT[j][colbase]);
        const float mj = means[(size_t)k * DD + j];
        const float wj = wv[(size_t)k * DD + j];
        sacc[0] = fmaf(dv.x - mj, y[jc][0][b] - wj, sacc[0]);
        sacc[1] = fmaf(dv.y - mj, y[jc][1][b] - wj, sacc[1]);
        sacc[2] = fmaf(dv.z - mj, y[jc][2][b] - wj, sacc[2]);
        sacc[3] = fmaf(dv.w - mj, y[jc][3][b] - wj, sacc[3]);
      }
    }

    float* qred = &Pl[0][0];  // 2048 floats needed, Pl (4096) dead now
    #pragma unroll
    for (int a = 0; a < 4; ++a)
      qred[tj * 64 + tn * 4 + a] = sacc[a];
    __syncthreads();

    if (tid < 64) {
      float qv = 0.0f;
      #pragma unroll
      for (int t = 0; t < 16; ++t) qv += qred[t * 64 + tid];
      // q' = dev^T S dev = -quad  ->  lp = cA + 0.5*q'
      lp[(size_t)(n0 + tid) * KC + k] = fmaf(0.5f, qv, cA[k]);
    }
  }
}

// ---------------- Kernel 3: row softmax over K+1 = 65 entries -----------------
__global__ __launch_bounds__(64) void softmax_kernel(
    const float* __restrict__ lp, const int* __restrict__ n_points_p,
    float* __restrict__ out)
{
  const int n = blockIdx.x;
  const int l = threadIdx.x;
  const float denom = (float)(*n_points_p) + 1.0f;
  const float log_new = -logf(denom);  // log(ALPHA/denom), ALPHA=1

  float v = lp[(size_t)n * KC + l];
  float m = v;
  #pragma unroll
  for (int off = 32; off > 0; off >>= 1) m = fmaxf(m, __shfl_xor(m, off, 64));
  m = fmaxf(m, log_new);

  float e = expf(v - m);
  float s = e;
  #pragma unroll
  for (int off = 32; off > 0; off >>= 1) s += __shfl_xor(s, off, 64);
  float enew = expf(log_new - m);
  s += enew;

  out[(size_t)n * (KC + 1) + l] = e / s;
  if (l == 0) out[(size_t)n * (KC + 1) + KC] = enew / s;
}

extern "C" void kernel_launch(void* const* d_in, const int* in_sizes, int n_in,
                              void* d_out, int out_size, void* d_ws, size_t ws_size,
                              hipStream_t stream)
{
  const float* x       = (const float*)d_in[0];  // [N, D]
  const float* means   = (const float*)d_in[1];  // [K, D]
  const float* covs    = (const float*)d_in[2];  // [K, D, D]
  const float* counts  = (const float*)d_in[3];  // [K]
  const int*   n_points = (const int*)d_in[4];   // scalar

  float* S   = (float*)d_ws;                      // K*D*D
  float* cA  = S + (size_t)KC * DD * DD;          // K
  float* ldp = cA + KC;                           // 4*K
  float* lp  = ldp + 4 * KC;                      // N*K
  float* Plbuf = lp;  // alias: Plbuf (K*64*64 = N*K floats) used only during
                      // sweep; lp written only by quad afterwards.
  float* out = (float*)d_out;                     // [N, K+1]
  // wv = S_k*mu_k staged in the out buffer (64KB of 1MB); quad reads it before
  // softmax overwrites out — stream-ordered, safe.
  float* wv = out;

  for (int bs = 0; bs < 4; ++bs) {
    pivot_kernel<<<KC, 512, 0, stream>>>(covs, counts, n_points, S, Plbuf, ldp, cA, bs);
    update_kernel<<<dim3(KC, 3), 512, 0, stream>>>(covs, S, Plbuf, bs);
  }
  pivot_kernel<<<KC, 512, 0, stream>>>(covs, counts, n_points, S, Plbuf, ldp, cA, 4);
  w_kernel<<<KC, 256, 0, stream>>>(S, means, wv);
  quad_kernel<<<dim3(NPTS / NT, KC / KG), 256, 0, stream>>>(x, means, S, cA, wv, lp);
  softmax_kernel<<<NPTS, 64, 0, stream>>>(lp, n_points, out);
}

// Round 4
// 866.895 us; speedup vs baseline: 8.1192x; 1.1349x over previous
//
#include <hip/hip_runtime.h>
#include <math.h>

// StreamingDPM: probs = softmax([ -0.5*(D log2pi + logdet_k + quad_nk) + log_prior_k | log_new ])
// N=4096 D=256 K=64, out [N, K+1] fp32.
//
// ws layout (floats):
//   S    : K*D*D  (sweep result; holds -Sigma^{-1} after all steps)
//   cA   : K      (log_prior_k - 0.5*(D log2pi + logdet_k))
//   ldp  : 4*K    (per-block-step logdet partials)
//   lp   : N*K    (log-probs before softmax; ALIASED as Plbuf during sweep)
// wv (= S_k * mu_k, [K][D]) lives in the OUTPUT buffer temporarily (quad reads
// it before softmax overwrites out; stream-ordered, safe).

#define DD 256
#define KC 64
#define NPTS 4096
#define NT 64
#define BB 64          // sweep block size
#define KG 8           // clusters per quad block
#define CH 8           // S chunk rows staged per quad step
#define NCH (DD / CH)  // 32 chunks

// ---------------- Kernel 1a: pivot-block sweep (+ deferred J-col writeback) --
__global__ __launch_bounds__(512) void pivot_kernel(
    const float* __restrict__ covs, const float* __restrict__ counts,
    const int* __restrict__ n_points_p, float* __restrict__ S,
    float* __restrict__ Plbuf, float* __restrict__ ldp, float* __restrict__ cA,
    int bs)
{
  const int k = blockIdx.x;
  const int tid = threadIdx.x;
  __shared__ __align__(16) float Pl[BB][BB + 4];
  __shared__ __align__(16) float pivr[BB];
  __shared__ __align__(16) float pivc[BB];
  float* Pb = Plbuf + (size_t)k * BB * BB;

  if (bs > 0) {
    // ---- deferred write of step bs-1's J columns:
    //  M[J,J] = -P^{-1} = Pl_prev ;  M[I,J] = C*P^{-1} = -(C*Pl_prev)
    const int j0p = (bs - 1) * BB;
    const float* src = ((bs == 1) ? covs : (const float*)S) + (size_t)k * DD * DD;
    float* dstm = S + (size_t)k * DD * DD;
    #pragma unroll
    for (int q = 0; q < 8; ++q) {
      int e = q * 512 + tid;
      Pl[e >> 6][e & 63] = Pb[e];
    }
    __syncthreads();
    const int r = tid & 255;
    const int h = (tid >> 8) * 32;
    const bool inJ = (r >= j0p) && (r < j0p + BB);  // wave-uniform (64-aligned)
    if (inJ) {
      #pragma unroll
      for (int c = 0; c < 32; c += 4) {
        *reinterpret_cast<float4*>(&dstm[(size_t)r * DD + j0p + h + c]) =
            *reinterpret_cast<const float4*>(&Pl[r - j0p][h + c]);
      }
    } else {
      float Crow[BB];
      #pragma unroll
      for (int p = 0; p < BB; p += 4) {
        float4 cv = *reinterpret_cast<const float4*>(&src[(size_t)r * DD + j0p + p]);
        Crow[p] = cv.x; Crow[p + 1] = cv.y; Crow[p + 2] = cv.z; Crow[p + 3] = cv.w;
      }
      #pragma unroll
      for (int c = 0; c < 32; c += 4) {
        float ax = 0.f, ay = 0.f, az = 0.f, aw = 0.f;
        #pragma unroll
        for (int p = 0; p < BB; ++p) {
          float4 pv = *reinterpret_cast<const float4*>(&Pl[p][h + c]);
          ax = fmaf(Crow[p], pv.x, ax);
          ay = fmaf(Crow[p], pv.y, ay);
          az = fmaf(Crow[p], pv.z, az);
          aw = fmaf(Crow[p], pv.w, aw);
        }
        float4 o = {-ax, -ay, -az, -aw};
        *reinterpret_cast<float4*>(&dstm[(size_t)r * DD + j0p + h + c]) = o;
      }
    }
    __syncthreads();  // Pl about to be reused
  }

  if (bs == 4) {  // final flush: assemble cA
    if (tid == 0) {
      float denom = (float)(*n_points_p) + 1.0f;  // ALPHA = 1
      float ld = ldp[k] + ldp[KC + k] + ldp[2 * KC + k] + ldp[3 * KC + k];
      // D*log(2*pi) = 256 * 1.8378770664093453
      cA[k] = logf(counts[k] / denom) - 0.5f * (470.49652900079047f + ld);
    }
    return;
  }

  // ---- load pivot block P = S[J,J] (step 0: from covs); row-contig float4
  // ownership: thread = (row pr = tid>>3, cols pc..pc+7).
  const int j0 = bs * BB;
  const float* psrc = ((bs == 0) ? covs : (const float*)S) + (size_t)k * DD * DD;
  const int pr = tid >> 3;
  const int pc = (tid & 7) * 8;
  {
    float4 a = *reinterpret_cast<const float4*>(&psrc[(size_t)(j0 + pr) * DD + j0 + pc]);
    float4 b = *reinterpret_cast<const float4*>(&psrc[(size_t)(j0 + pr) * DD + j0 + pc + 4]);
    *reinterpret_cast<float4*>(&Pl[pr][pc]) = a;
    *reinterpret_cast<float4*>(&Pl[pr][pc + 4]) = b;
  }
  __syncthreads();

  float ld = 0.0f;
  for (int p = 0; p < BB; ++p) {
    if (tid < BB) { pivc[tid] = Pl[tid][p]; pivr[tid] = Pl[p][tid]; }
    __syncthreads();
    const float d = pivc[p];
    const float inv_d = 1.0f / d;
    if (tid == 0) ld += logf(d);

    const float cr = pivc[pr];
    float v[8], rw[8];
    *reinterpret_cast<float4*>(&v[0]) = *reinterpret_cast<const float4*>(&Pl[pr][pc]);
    *reinterpret_cast<float4*>(&v[4]) = *reinterpret_cast<const float4*>(&Pl[pr][pc + 4]);
    *reinterpret_cast<float4*>(&rw[0]) = *reinterpret_cast<const float4*>(&pivr[pc]);
    *reinterpret_cast<float4*>(&rw[4]) = *reinterpret_cast<const float4*>(&pivr[pc + 4]);
    #pragma unroll
    for (int e = 0; e < 8; ++e) {
      float ge = fmaf(-inv_d * cr, rw[e], v[e]);     // general update
      if (pr == p)     ge = rw[e] * inv_d;           // row p
      if (pc + e == p) ge = (pr == p) ? -inv_d : cr * inv_d;  // col p / diag
      v[e] = ge;
    }
    *reinterpret_cast<float4*>(&Pl[pr][pc])     = *reinterpret_cast<const float4*>(&v[0]);
    *reinterpret_cast<float4*>(&Pl[pr][pc + 4]) = *reinterpret_cast<const float4*>(&v[4]);
    __syncthreads();
  }

  // ---- store Pl = -P^{-1} for the update/deferred kernels (coalesced)
  *reinterpret_cast<float4*>(&Pb[pr * BB + pc]) =
      *reinterpret_cast<const float4*>(&Pl[pr][pc]);
  *reinterpret_cast<float4*>(&Pb[pr * BB + pc + 4]) =
      *reinterpret_cast<const float4*>(&Pl[pr][pc + 4]);
  if (tid == 0) ldp[bs * KC + k] = ld;
}

// ---------------- Kernel 1b: trailing update of one non-J column slice ------
// Block (k, si): slice t = si + (si>=bs), columns [t*64, t*64+64).
//   T'[:,slice] = Pl * S[J, slice]  (LDS GEMM)
//   rows in J:   M[J, slice] = -T'
//   rows not J:  M[I, slice] = Q + C*T'   with C = S[:,J] (untouched this step)
__global__ __launch_bounds__(512) void update_kernel(
    const float* __restrict__ covs, float* __restrict__ S,
    const float* __restrict__ Plbuf, int bs)
{
  const int k = blockIdx.x;
  const int si = blockIdx.y;
  const int t = si + (si >= bs ? 1 : 0);
  const int c0 = t * BB;
  const int j0 = bs * BB;
  const int tid = threadIdx.x;
  const float* src = ((bs == 0) ? covs : (const float*)S) + (size_t)k * DD * DD;
  float* dst = S + (size_t)k * DD * DD;

  __shared__ float Pl[BB][BB + 4];
  __shared__ float SJ[BB][BB + 4];
  __shared__ float Tl[BB][BB + 4];

  const float* Pb = Plbuf + (size_t)k * BB * BB;
  #pragma unroll
  for (int q = 0; q < 8; ++q) {
    int e = q * 512 + tid;
    int r = e >> 6, c = e & 63;
    Pl[r][c] = Pb[e];
    SJ[r][c] = src[(size_t)(j0 + r) * DD + c0 + c];
  }
  __syncthreads();

  // ---- T' = Pl * SJ  (thread: col c, 8 rows)
  {
    const int c = tid & 63;
    const int rg = (tid >> 6) * 8;
    float tv[8];
    #pragma unroll
    for (int r = 0; r < 8; ++r) tv[r] = 0.0f;
    for (int p = 0; p < BB; p += 4) {
      float s0 = SJ[p][c], s1 = SJ[p + 1][c], s2 = SJ[p + 2][c], s3 = SJ[p + 3][c];
      #pragma unroll
      for (int r = 0; r < 8; ++r) {
        float4 pv = *reinterpret_cast<const float4*>(&Pl[rg + r][p]);
        tv[r] = fmaf(pv.x, s0, fmaf(pv.y, s1, fmaf(pv.z, s2, fmaf(pv.w, s3, tv[r]))));
      }
    }
    #pragma unroll
    for (int r = 0; r < 8; ++r) Tl[rg + r][c] = tv[r];
  }
  __syncthreads();

  // ---- apply to this column slice (thread: row r, 32 cols)
  const int r = tid & 255;
  const int h = (tid >> 8) * 32;
  const bool inJ = (r >= j0) && (r < j0 + BB);  // wave-uniform
  if (inJ) {
    #pragma unroll
    for (int c = 0; c < 32; c += 4) {
      float4 tv4 = *reinterpret_cast<const float4*>(&Tl[r - j0][h + c]);
      float4 o = {-tv4.x, -tv4.y, -tv4.z, -tv4.w};
      *reinterpret_cast<float4*>(&dst[(size_t)r * DD + c0 + h + c]) = o;
    }
  } else {
    float Crow[BB];
    #pragma unroll
    for (int p = 0; p < BB; p += 4) {
      float4 cv = *reinterpret_cast<const float4*>(&src[(size_t)r * DD + j0 + p]);
      Crow[p] = cv.x; Crow[p + 1] = cv.y; Crow[p + 2] = cv.z; Crow[p + 3] = cv.w;
    }
    #pragma unroll
    for (int c = 0; c < 32; c += 4) {
      float4 acc = *reinterpret_cast<const float4*>(&src[(size_t)r * DD + c0 + h + c]);
      #pragma unroll
      for (int p = 0; p < BB; ++p) {
        float4 tv4 = *reinterpret_cast<const float4*>(&Tl[p][h + c]);
        acc.x = fmaf(Crow[p], tv4.x, acc.x);
        acc.y = fmaf(Crow[p], tv4.y, acc.y);
        acc.z = fmaf(Crow[p], tv4.z, acc.z);
        acc.w = fmaf(Crow[p], tv4.w, acc.w);
      }
      *reinterpret_cast<float4*>(&dst[(size_t)r * DD + c0 + h + c]) = acc;
    }
  }
}

// ---------------- Kernel 1c: wv_k = S_k * mu_k -------------------------------
__global__ __launch_bounds__(256) void w_kernel(
    const float* __restrict__ S, const float* __restrict__ means,
    float* __restrict__ wv)
{
  const int k = blockIdx.x;
  const int tid = threadIdx.x;
  const float* Sk = S + (size_t)k * DD * DD;
  __shared__ float mus[DD];
  mus[tid] = means[(size_t)k * DD + tid];
  __syncthreads();
  float a0 = 0.f, a1 = 0.f, a2 = 0.f, a3 = 0.f;
  for (int j = 0; j < DD; j += 4) {
    a0 = fmaf(Sk[(size_t)(j + 0) * DD + tid], mus[j + 0], a0);
    a1 = fmaf(Sk[(size_t)(j + 1) * DD + tid], mus[j + 1], a1);
    a2 = fmaf(Sk[(size_t)(j + 2) * DD + tid], mus[j + 2], a2);
    a3 = fmaf(Sk[(size_t)(j + 3) * DD + tid], mus[j + 3], a3);
  }
  wv[(size_t)k * DD + tid] = (a0 + a1) + (a2 + a3);
}

// ---------------- Kernel 2: quad via mean-folded GEMM ------------------------
// dev^T S dev = sum_j (x_j - mu_j) * ((X*S)_nj - wv_j)   (S symmetric).
// X-tile (64 points) is k-independent -> staged once, KG=8 clusters per block.
// S_k streamed in CH=8-row chunks, register-prefetched (2x float4, no spill).
// XT point-index XOR-swizzled. lp buffered in LDS, written coalesced at end.
// LDS = 64+8+2+2 = 76 KB -> 2 blocks/CU.
__global__ __launch_bounds__(256, 2) void quad_kernel(
    const float* __restrict__ X, const float* __restrict__ means,
    const float* __restrict__ S, const float* __restrict__ cA,
    const float* __restrict__ wv, float* __restrict__ lp)
{
  __shared__ float XT[DD][NT];   // (i,r) stored at XT[i][r ^ (((i>>2)&15)<<2)]
  __shared__ float Pl[CH][DD];   // S chunk; reused as reduction buffer
  __shared__ float muw[2][DD];   // mu_k, wv_k
  __shared__ float lpb[KG][NT];  // per-k results, flushed coalesced at end

  const int tid = threadIdx.x;
  const int n0 = blockIdx.x * NT;
  const int k0 = blockIdx.y * KG;

  // stage X tile transposed + swizzled (once per block)
  #pragma unroll
  for (int q = 0; q < 16; ++q) {
    int f = q * 1024 + tid * 4;
    int r = f >> 8;
    int c = f & 255;
    float4 xv = *reinterpret_cast<const float4*>(X + (size_t)(n0 + r) * DD + c);
    int rs = r ^ (((c >> 2) & 15) << 2);
    XT[c + 0][rs] = xv.x;
    XT[c + 1][rs] = xv.y;
    XT[c + 2][rs] = xv.z;
    XT[c + 3][rs] = xv.w;
  }

  const int tn = tid & 15;   // n sub-tile: rows tn*4 .. +3
  const int tj = tid >> 4;   // j sub-tile within each 64-wide jc block
  const int f0 = tid * 4;
  const int f1 = 1024 + tid * 4;

  #pragma unroll 1
  for (int kk = 0; kk < KG; ++kk) {
    const int k = k0 + kk;
    const float* Sk = S + (size_t)k * DD * DD;

    __syncthreads();  // prev k's Pl/muw readers done; XT staged (kk==0)
    muw[0][tid] = means[(size_t)k * DD + tid];
    muw[1][tid] = wv[(size_t)k * DD + tid];

    // prologue: chunk 0 -> registers
    float4 pre0 = *reinterpret_cast<const float4*>(Sk + (size_t)(f0 >> 8) * DD + (f0 & 255));
    float4 pre1 = *reinterpret_cast<const float4*>(Sk + (size_t)(f1 >> 8) * DD + (f1 & 255));

    float y[4][4][4];  // [jc][a][b]
    #pragma unroll
    for (int jc = 0; jc < 4; ++jc)
      #pragma unroll
      for (int a = 0; a < 4; ++a)
        #pragma unroll
        for (int b = 0; b < 4; ++b)
          y[jc][a][b] = 0.0f;

    #pragma unroll 1
    for (int ct = 0; ct < NCH; ++ct) {
      __syncthreads();  // Pl free (prev chunk consumed); muw/XT visible
      *reinterpret_cast<float4*>(&Pl[f0 >> 8][f0 & 255]) = pre0;
      *reinterpret_cast<float4*>(&Pl[f1 >> 8][f1 & 255]) = pre1;
      if (ct < NCH - 1) {  // issue next chunk's loads; in flight across compute
        const float* srcp = Sk + (size_t)(ct + 1) * CH * DD;
        pre0 = *reinterpret_cast<const float4*>(srcp + (size_t)(f0 >> 8) * DD + (f0 & 255));
        pre1 = *reinterpret_cast<const float4*>(srcp + (size_t)(f1 >> 8) * DD + (f1 & 255));
      }
      __syncthreads();  // Pl ready

      #pragma unroll
      for (int il = 0; il < CH; ++il) {
        const int i = ct * CH + il;
        const int sw = ((i >> 2) & 15) << 2;
        float4 xv = *reinterpret_cast<const float4*>(&XT[i][(tn * 4) ^ sw]);
        #pragma unroll
        for (int jc = 0; jc < 4; ++jc) {
          float4 pv = *reinterpret_cast<const float4*>(&Pl[il][jc * 64 + tj * 4]);
          y[jc][0][0] = fmaf(xv.x, pv.x, y[jc][0][0]);
          y[jc][0][1] = fmaf(xv.x, pv.y, y[jc][0][1]);
          y[jc][0][2] = fmaf(xv.x, pv.z, y[jc][0][2]);
          y[jc][0][3] = fmaf(xv.x, pv.w, y[jc][0][3]);
          y[jc][1][0] = fmaf(xv.y, pv.x, y[jc][1][0]);
          y[jc][1][1] = fmaf(xv.y, pv.y, y[jc][1][1]);
          y[jc][1][2] = fmaf(xv.y, pv.z, y[jc][1][2]);
          y[jc][1][3] = fmaf(xv.y, pv.w, y[jc][1][3]);
          y[jc][2][0] = fmaf(xv.z, pv.x, y[jc][2][0]);
          y[jc][2][1] = fmaf(xv.z, pv.y, y[jc][2][1]);
          y[jc][2][2] = fmaf(xv.z, pv.z, y[jc][2][2]);
          y[jc][2][3] = fmaf(xv.z, pv.w, y[jc][2][3]);
          y[jc][3][0] = fmaf(xv.w, pv.x, y[jc][3][0]);
          y[jc][3][1] = fmaf(xv.w, pv.y, y[jc][3][1]);
          y[jc][3][2] = fmaf(xv.w, pv.z, y[jc][3][2]);
          y[jc][3][3] = fmaf(xv.w, pv.w, y[jc][3][3]);
        }
      }
    }
    __syncthreads();  // all threads done reading Pl before qred reuse

    // epilogue: q'[n] = sum_j (x[n,j]-mu_j) * (y[n,j]-wv_j)
    float sacc[4] = {0.0f, 0.0f, 0.0f, 0.0f};
    const int colbase = (tn * 4) ^ (tj << 2);  // swizzle for rows j: sw_j == tj<<2
    #pragma unroll
    for (int jc = 0; jc < 4; ++jc) {
      #pragma unroll
      for (int b = 0; b < 4; ++b) {
        const int j = jc * 64 + tj * 4 + b;
        float4 dv = *reinterpret_cast<const float4*>(&XT[j][colbase]);
        const float mj = muw[0][j];
        const float wj = muw[1][j];
        sacc[0] = fmaf(dv.x - mj, y[jc][0][b] - wj, sacc[0]);
        sacc[1] = fmaf(dv.y - mj, y[jc][1][b] - wj, sacc[1]);
        sacc[2] = fmaf(dv.z - mj, y[jc][2][b] - wj, sacc[2]);
        sacc[3] = fmaf(dv.w - mj, y[jc][3][b] - wj, sacc[3]);
      }
    }

    float* qred = &Pl[0][0];  // 2048 floats, Pl dead now
    #pragma unroll
    for (int a = 0; a < 4; ++a)
      qred[tj * 64 + tn * 4 + a] = sacc[a];
    __syncthreads();

    if (tid < 64) {
      float qv = 0.0f;
      #pragma unroll
      for (int t = 0; t < 16; ++t) qv += qred[t * 64 + tid];
      // q' = dev^T S dev = -quad  ->  lp = cA + 0.5*q'
      lpb[kk][tid] = fmaf(0.5f, qv, cA[k]);
    }
  }

  // coalesced lp flush: 2 float4 per point row (8 k values)
  __syncthreads();
  if (tid < 128) {
    const int n = tid >> 1;
    const int h = (tid & 1) * 4;
    float4 o = {lpb[h + 0][n], lpb[h + 1][n], lpb[h + 2][n], lpb[h + 3][n]};
    *reinterpret_cast<float4*>(&lp[(size_t)(n0 + n) * KC + k0 + h]) = o;
  }
}

// ---------------- Kernel 3: row softmax over K+1 = 65 entries -----------------
__global__ __launch_bounds__(64) void softmax_kernel(
    const float* __restrict__ lp, const int* __restrict__ n_points_p,
    float* __restrict__ out)
{
  const int n = blockIdx.x;
  const int l = threadIdx.x;
  const float denom = (float)(*n_points_p) + 1.0f;
  const float log_new = -logf(denom);  // log(ALPHA/denom), ALPHA=1

  float v = lp[(size_t)n * KC + l];
  float m = v;
  #pragma unroll
  for (int off = 32; off > 0; off >>= 1) m = fmaxf(m, __shfl_xor(m, off, 64));
  m = fmaxf(m, log_new);

  float e = expf(v - m);
  float s = e;
  #pragma unroll
  for (int off = 32; off > 0; off >>= 1) s += __shfl_xor(s, off, 64);
  float enew = expf(log_new - m);
  s += enew;

  out[(size_t)n * (KC + 1) + l] = e / s;
  if (l == 0) out[(size_t)n * (KC + 1) + KC] = enew / s;
}

extern "C" void kernel_launch(void* const* d_in, const int* in_sizes, int n_in,
                              void* d_out, int out_size, void* d_ws, size_t ws_size,
                              hipStream_t stream)
{
  const float* x       = (const float*)d_in[0];  // [N, D]
  const float* means   = (const float*)d_in[1];  // [K, D]
  const float* covs    = (const float*)d_in[2];  // [K, D, D]
  const float* counts  = (const float*)d_in[3];  // [K]
  const int*   n_points = (const int*)d_in[4];   // scalar

  float* S   = (float*)d_ws;                      // K*D*D
  float* cA  = S + (size_t)KC * DD * DD;          // K
  float* ldp = cA + KC;                           // 4*K
  float* lp  = ldp + 4 * KC;                      // N*K
  float* Plbuf = lp;  // alias: Plbuf (K*64*64 = N*K floats) used only during
                      // sweep; lp written only by quad afterwards.
  float* out = (float*)d_out;                     // [N, K+1]
  // wv = S_k*mu_k staged in the out buffer (64KB of 1MB); quad reads it before
  // softmax overwrites out — stream-ordered, safe.
  float* wv = out;

  for (int bs = 0; bs < 4; ++bs) {
    pivot_kernel<<<KC, 512, 0, stream>>>(covs, counts, n_points, S, Plbuf, ldp, cA, bs);
    update_kernel<<<dim3(KC, 3), 512, 0, stream>>>(covs, S, Plbuf, bs);
  }
  pivot_kernel<<<KC, 512, 0, stream>>>(covs, counts, n_points, S, Plbuf, ldp, cA, 4);
  w_kernel<<<KC, 256, 0, stream>>>(S, means, wv);
  quad_kernel<<<dim3(NPTS / NT, KC / KG), 256, 0, stream>>>(x, means, S, cA, wv, lp);
  softmax_kernel<<<NPTS, 64, 0, stream>>>(lp, n_points, out);
}

// Round 5
// 776.921 us; speedup vs baseline: 9.0594x; 1.1158x over previous
//
#include <hip/hip_runtime.h>
#include <math.h>

// StreamingDPM: probs = softmax([ -0.5*(D log2pi + logdet_k + quad_nk) + log_prior_k | log_new ])
// N=4096 D=256 K=64, out [N, K+1] fp32.
//
// ws layout (floats):
//   S    : K*D*D  (sweep result; holds -Sigma^{-1} after all steps)
//   cA   : K      (log_prior_k - 0.5*(D log2pi + logdet_k))
//   ldp  : 4*K    (per-block-step logdet partials)
//   lp   : N*K    (log-probs before softmax; ALIASED as Plbuf during sweep)
// wv (= S_k * mu_k, [K][D]) lives in the OUTPUT buffer temporarily (quad reads
// it before softmax overwrites out; stream-ordered, safe).
//
// Sweep schedule (per block step bs): pivot_kernel grid (K,5):
//   by<4  : deferred J-column writeback of step bs-1 (parallel, 64 rows each)
//   by==4 : register-resident sweep of the 64x64 pivot block (1 barrier/pivot)
// then update_kernel (K,3): trailing update of the 3 non-J column slices.
// J-col writes are deferred one launch so no block writes S[:,J] while another
// reads C = S[:,J]. Step 0 reads covs directly.

#define DD 256
#define KC 64
#define NPTS 4096
#define NT 64
#define BB 64          // sweep block size
#define KG 8           // clusters per quad block (processed as 4 pairs)
#define CH 4           // S chunk rows staged per quad step (per cluster)
#define NCH (DD / CH)  // 64 chunks

// ---------------- Kernel 1a: pivot sweep + deferred J-col writeback ----------
__global__ __launch_bounds__(512) void pivot_kernel(
    const float* __restrict__ covs, float* __restrict__ S,
    float* __restrict__ Plbuf, float* __restrict__ ldp, int bs)
{
  const int k = blockIdx.x;
  const int by = blockIdx.y;
  const int tid = threadIdx.x;
  float* Pb = Plbuf + (size_t)k * BB * BB;

  __shared__ __align__(16) float Tl[BB][BB + 4];
  __shared__ __align__(16) float pivc[2][BB];
  __shared__ __align__(16) float pivr[2][BB];

  if (by < 4) {
    // ---- deferred write of step bs-1's J columns (rows r0..r0+63):
    //  M[J,J] = -P^{-1} = Pb ;  M[I,J] = C*P^{-1} = -(C*Pb)
    if (bs == 0) return;
    const int j0p = (bs - 1) * BB;
    const int r0 = by * BB;
    const float* src = ((bs == 1) ? covs : (const float*)S) + (size_t)k * DD * DD;
    float* dst = S + (size_t)k * DD * DD;

    const int rr = tid >> 3;         // 0..63
    const int cc = (tid & 7) * 8;    // 0..56
    *reinterpret_cast<float4*>(&Tl[rr][cc]) =
        *reinterpret_cast<const float4*>(&Pb[rr * BB + cc]);
    *reinterpret_cast<float4*>(&Tl[rr][cc + 4]) =
        *reinterpret_cast<const float4*>(&Pb[rr * BB + cc + 4]);
    __syncthreads();

    const int r = r0 + rr;
    if (r0 == j0p) {
      // rows in J: direct copy of -P^{-1}
      *reinterpret_cast<float4*>(&dst[(size_t)r * DD + j0p + cc]) =
          *reinterpret_cast<const float4*>(&Tl[rr][cc]);
      *reinterpret_cast<float4*>(&dst[(size_t)r * DD + j0p + cc + 4]) =
          *reinterpret_cast<const float4*>(&Tl[rr][cc + 4]);
    } else {
      float Crow[BB];
      #pragma unroll
      for (int p = 0; p < BB; p += 4) {
        float4 cv = *reinterpret_cast<const float4*>(&src[(size_t)r * DD + j0p + p]);
        Crow[p] = cv.x; Crow[p + 1] = cv.y; Crow[p + 2] = cv.z; Crow[p + 3] = cv.w;
      }
      float acc[8] = {0.f, 0.f, 0.f, 0.f, 0.f, 0.f, 0.f, 0.f};
      #pragma unroll
      for (int p = 0; p < BB; ++p) {
        float4 t0 = *reinterpret_cast<const float4*>(&Tl[p][cc]);
        float4 t1 = *reinterpret_cast<const float4*>(&Tl[p][cc + 4]);
        acc[0] = fmaf(Crow[p], t0.x, acc[0]);
        acc[1] = fmaf(Crow[p], t0.y, acc[1]);
        acc[2] = fmaf(Crow[p], t0.z, acc[2]);
        acc[3] = fmaf(Crow[p], t0.w, acc[3]);
        acc[4] = fmaf(Crow[p], t1.x, acc[4]);
        acc[5] = fmaf(Crow[p], t1.y, acc[5]);
        acc[6] = fmaf(Crow[p], t1.z, acc[6]);
        acc[7] = fmaf(Crow[p], t1.w, acc[7]);
      }
      float4 o0 = {-acc[0], -acc[1], -acc[2], -acc[3]};
      float4 o1 = {-acc[4], -acc[5], -acc[6], -acc[7]};
      *reinterpret_cast<float4*>(&dst[(size_t)r * DD + j0p + cc]) = o0;
      *reinterpret_cast<float4*>(&dst[(size_t)r * DD + j0p + cc + 4]) = o1;
    }
    return;
  }

  if (bs == 4) return;  // flush launch: defer blocks only

  // ---- register-resident sweep of P = S[J,J] (step 0: from covs).
  // Thread owns row pr, cols pc..pc+7 in VGPRs for all 64 pivots; only the
  // pivot row/col is exchanged via double-buffered LDS. 1 barrier per pivot.
  const int j0 = bs * BB;
  const float* psrc = ((bs == 0) ? covs : (const float*)S) + (size_t)k * DD * DD;
  const int pr = tid >> 3;
  const int pc = (tid & 7) * 8;

  float v[8];
  {
    float4 a4 = *reinterpret_cast<const float4*>(&psrc[(size_t)(j0 + pr) * DD + j0 + pc]);
    float4 b4 = *reinterpret_cast<const float4*>(&psrc[(size_t)(j0 + pr) * DD + j0 + pc + 4]);
    v[0] = a4.x; v[1] = a4.y; v[2] = a4.z; v[3] = a4.w;
    v[4] = b4.x; v[5] = b4.y; v[6] = b4.z; v[7] = b4.w;
  }
  if (pc == 0) pivc[0][pr] = v[0];
  if (pr == 0) {
    #pragma unroll
    for (int e = 0; e < 8; ++e) pivr[0][pc + e] = v[e];
  }
  __syncthreads();

  float ld = 0.0f;
  #pragma unroll 1
  for (int p = 0; p < BB; ++p) {
    const int cur = p & 1, nxt = cur ^ 1;
    const float d = pivc[cur][p];
    const float inv_d = 1.0f / d;
    if (tid == 0) ld += logf(d);
    const float cr = pivc[cur][pr];
    float rw[8];
    *reinterpret_cast<float4*>(&rw[0]) = *reinterpret_cast<const float4*>(&pivr[cur][pc]);
    *reinterpret_cast<float4*>(&rw[4]) = *reinterpret_cast<const float4*>(&pivr[cur][pc + 4]);
    #pragma unroll
    for (int e = 0; e < 8; ++e) {
      float ge = fmaf(-inv_d * cr, rw[e], v[e]);         // general update
      if (pr == p)     ge = rw[e] * inv_d;               // pivot row
      if (pc + e == p) ge = (pr == p) ? -inv_d : cr * inv_d;  // pivot col/diag
      v[e] = ge;
    }
    if (p < BB - 1) {
      if (pr == p + 1) {
        #pragma unroll
        for (int e = 0; e < 8; ++e) pivr[nxt][pc + e] = v[e];
      }
      if (pc <= p + 1 && p + 1 < pc + 8) pivc[nxt][pr] = v[p + 1 - pc];
    }
    __syncthreads();
  }

  // store -P^{-1} for the update/deferred kernels (coalesced)
  float4 s0 = {v[0], v[1], v[2], v[3]};
  float4 s1 = {v[4], v[5], v[6], v[7]};
  *reinterpret_cast<float4*>(&Pb[pr * BB + pc]) = s0;
  *reinterpret_cast<float4*>(&Pb[pr * BB + pc + 4]) = s1;
  if (tid == 0) ldp[bs * KC + k] = ld;
}

// ---------------- Kernel 1b: trailing update of one non-J column slice ------
__global__ __launch_bounds__(512) void update_kernel(
    const float* __restrict__ covs, float* __restrict__ S,
    const float* __restrict__ Plbuf, int bs)
{
  const int k = blockIdx.x;
  const int si = blockIdx.y;
  const int t = si + (si >= bs ? 1 : 0);
  const int c0 = t * BB;
  const int j0 = bs * BB;
  const int tid = threadIdx.x;
  const float* src = ((bs == 0) ? covs : (const float*)S) + (size_t)k * DD * DD;
  float* dst = S + (size_t)k * DD * DD;

  __shared__ __align__(16) float Pl[BB][BB + 4];
  __shared__ __align__(16) float SJ[BB][BB + 4];
  __shared__ __align__(16) float Tl[BB][BB + 4];

  const float* Pb = Plbuf + (size_t)k * BB * BB;
  #pragma unroll
  for (int q = 0; q < 8; ++q) {
    int e = q * 512 + tid;
    int r = e >> 6, c = e & 63;
    Pl[r][c] = Pb[e];
    SJ[r][c] = src[(size_t)(j0 + r) * DD + c0 + c];
  }
  __syncthreads();

  // ---- T' = Pl * SJ  (thread: col c, 8 rows)
  {
    const int c = tid & 63;
    const int rg = (tid >> 6) * 8;
    float tv[8];
    #pragma unroll
    for (int r = 0; r < 8; ++r) tv[r] = 0.0f;
    for (int p = 0; p < BB; p += 4) {
      float s0 = SJ[p][c], s1 = SJ[p + 1][c], s2 = SJ[p + 2][c], s3 = SJ[p + 3][c];
      #pragma unroll
      for (int r = 0; r < 8; ++r) {
        float4 pv = *reinterpret_cast<const float4*>(&Pl[rg + r][p]);
        tv[r] = fmaf(pv.x, s0, fmaf(pv.y, s1, fmaf(pv.z, s2, fmaf(pv.w, s3, tv[r]))));
      }
    }
    #pragma unroll
    for (int r = 0; r < 8; ++r) Tl[rg + r][c] = tv[r];
  }
  __syncthreads();

  // ---- apply to this column slice (thread: row r, 32 cols)
  const int r = tid & 255;
  const int h = (tid >> 8) * 32;
  const bool inJ = (r >= j0) && (r < j0 + BB);  // wave-uniform
  if (inJ) {
    #pragma unroll
    for (int c = 0; c < 32; c += 4) {
      float4 tv4 = *reinterpret_cast<const float4*>(&Tl[r - j0][h + c]);
      float4 o = {-tv4.x, -tv4.y, -tv4.z, -tv4.w};
      *reinterpret_cast<float4*>(&dst[(size_t)r * DD + c0 + h + c]) = o;
    }
  } else {
    float Crow[BB];
    #pragma unroll
    for (int p = 0; p < BB; p += 4) {
      float4 cv = *reinterpret_cast<const float4*>(&src[(size_t)r * DD + j0 + p]);
      Crow[p] = cv.x; Crow[p + 1] = cv.y; Crow[p + 2] = cv.z; Crow[p + 3] = cv.w;
    }
    #pragma unroll
    for (int c = 0; c < 32; c += 4) {
      float4 acc = *reinterpret_cast<const float4*>(&src[(size_t)r * DD + c0 + h + c]);
      #pragma unroll
      for (int p = 0; p < BB; ++p) {
        float4 tv4 = *reinterpret_cast<const float4*>(&Tl[p][h + c]);
        acc.x = fmaf(Crow[p], tv4.x, acc.x);
        acc.y = fmaf(Crow[p], tv4.y, acc.y);
        acc.z = fmaf(Crow[p], tv4.z, acc.z);
        acc.w = fmaf(Crow[p], tv4.w, acc.w);
      }
      *reinterpret_cast<float4*>(&dst[(size_t)r * DD + c0 + h + c]) = acc;
    }
  }
}

// ---------------- Kernel 1c: wv_k = S_k * mu_k ; cA assembly -----------------
__global__ __launch_bounds__(256) void w_kernel(
    const float* __restrict__ S, const float* __restrict__ means,
    const float* __restrict__ counts, const int* __restrict__ n_points_p,
    const float* __restrict__ ldp, float* __restrict__ cA,
    float* __restrict__ wv)
{
  const int k = blockIdx.x;
  const int tid = threadIdx.x;
  if (tid == 0) {
    float denom = (float)(*n_points_p) + 1.0f;  // ALPHA = 1
    float ld = ldp[k] + ldp[KC + k] + ldp[2 * KC + k] + ldp[3 * KC + k];
    // D*log(2*pi) = 256 * 1.8378770664093453
    cA[k] = logf(counts[k] / denom) - 0.5f * (470.49652900079047f + ld);
  }
  const float* Sk = S + (size_t)k * DD * DD;
  __shared__ float mus[DD];
  mus[tid] = means[(size_t)k * DD + tid];
  __syncthreads();
  float a0 = 0.f, a1 = 0.f, a2 = 0.f, a3 = 0.f;
  for (int j = 0; j < DD; j += 4) {
    a0 = fmaf(Sk[(size_t)(j + 0) * DD + tid], mus[j + 0], a0);
    a1 = fmaf(Sk[(size_t)(j + 1) * DD + tid], mus[j + 1], a1);
    a2 = fmaf(Sk[(size_t)(j + 2) * DD + tid], mus[j + 2], a2);
    a3 = fmaf(Sk[(size_t)(j + 3) * DD + tid], mus[j + 3], a3);
  }
  wv[(size_t)k * DD + tid] = (a0 + a1) + (a2 + a3);
}

// ---------------- Kernel 2: quad via mean-folded GEMM ------------------------
// dev^T S dev = sum_j (x_j - mu_j) * ((X*S)_nj - wv_j)   (S symmetric).
// 8n x 8j register tile, 2 clusters at once (XT reads shared): per il step
// 6 ds_read_b128 feed 128 FMAs (vs 5 per 64 before) -> LDS-pipe pressure 1.67x
// lower. KG=8 clusters per block as 4 pairs. S streamed in CH=4-row chunks,
// register-prefetched. LDS = 64+8+4+2 = 78 KB -> 2 blocks/CU.
__global__ __launch_bounds__(256, 2) void quad_kernel(
    const float* __restrict__ X, const float* __restrict__ means,
    const float* __restrict__ S, const float* __restrict__ cA,
    const float* __restrict__ wv, float* __restrict__ lp)
{
  __shared__ __align__(16) float XT[DD][NT];      // (i,r) at XT[i][r ^ (((i>>2)&15)<<2)]
  __shared__ __align__(16) float Pl2[2][CH * DD]; // S chunks (2 clusters); qred alias
  __shared__ __align__(16) float muw[2][2][DD];   // per-pair {mu, wv} x 2 clusters
  __shared__ __align__(16) float lpb[KG][NT];     // results, flushed coalesced

  const int tid = threadIdx.x;
  const int n0 = blockIdx.x * NT;
  const int k0 = blockIdx.y * KG;

  // stage X tile transposed + swizzled (once per block)
  #pragma unroll
  for (int q = 0; q < 16; ++q) {
    int f = q * 1024 + tid * 4;
    int r = f >> 8;
    int c = f & 255;
    float4 xv = *reinterpret_cast<const float4*>(X + (size_t)(n0 + r) * DD + c);
    int rs = r ^ (((c >> 2) & 15) << 2);
    XT[c + 0][rs] = xv.x;
    XT[c + 1][rs] = xv.y;
    XT[c + 2][rs] = xv.z;
    XT[c + 3][rs] = xv.w;
  }

  const int tn = tid & 7;    // n sub-tile: rows tn*8 .. +7
  const int tj = tid >> 3;   // j sub-tile: cols tj*8 .. +7

  #pragma unroll 1
  for (int kp = 0; kp < KG / 2; ++kp) {
    const int k1 = k0 + kp * 2;
    const int k2 = k1 + 1;
    const float* S1 = S + (size_t)k1 * DD * DD;
    const float* S2 = S + (size_t)k2 * DD * DD;

    __syncthreads();  // prev pair's qred/muw readers done; XT staged (kp==0)
    muw[0][0][tid] = means[(size_t)k1 * DD + tid];
    muw[0][1][tid] = wv[(size_t)k1 * DD + tid];
    muw[1][0][tid] = means[(size_t)k2 * DD + tid];
    muw[1][1][tid] = wv[(size_t)k2 * DD + tid];

    // prologue: chunk 0 of both clusters -> registers
    float4 pre0 = *reinterpret_cast<const float4*>(S1 + tid * 4);
    float4 pre1 = *reinterpret_cast<const float4*>(S2 + tid * 4);

    float y0[8][8], y1[8][8];
    #pragma unroll
    for (int a = 0; a < 8; ++a)
      #pragma unroll
      for (int b = 0; b < 8; ++b) { y0[a][b] = 0.0f; y1[a][b] = 0.0f; }

    #pragma unroll 1
    for (int ct = 0; ct < NCH; ++ct) {
      __syncthreads();  // Pl2 free (prev chunk consumed); muw/XT visible
      *reinterpret_cast<float4*>(&Pl2[0][tid * 4]) = pre0;
      *reinterpret_cast<float4*>(&Pl2[1][tid * 4]) = pre1;
      if (ct < NCH - 1) {  // next chunk's loads stay in flight across compute
        pre0 = *reinterpret_cast<const float4*>(S1 + (size_t)(ct + 1) * CH * DD + tid * 4);
        pre1 = *reinterpret_cast<const float4*>(S2 + (size_t)(ct + 1) * CH * DD + tid * 4);
      }
      __syncthreads();  // Pl2 ready

      #pragma unroll
      for (int il = 0; il < CH; ++il) {
        const int i = ct * CH + il;
        const int sw = ((i >> 2) & 15) << 2;
        float xv[8], p0[8], p1[8];
        *reinterpret_cast<float4*>(&xv[0]) =
            *reinterpret_cast<const float4*>(&XT[i][(tn * 8) ^ sw]);
        *reinterpret_cast<float4*>(&xv[4]) =
            *reinterpret_cast<const float4*>(&XT[i][(tn * 8 + 4) ^ sw]);
        *reinterpret_cast<float4*>(&p0[0]) =
            *reinterpret_cast<const float4*>(&Pl2[0][il * DD + tj * 8]);
        *reinterpret_cast<float4*>(&p0[4]) =
            *reinterpret_cast<const float4*>(&Pl2[0][il * DD + tj * 8 + 4]);
        *reinterpret_cast<float4*>(&p1[0]) =
            *reinterpret_cast<const float4*>(&Pl2[1][il * DD + tj * 8]);
        *reinterpret_cast<float4*>(&p1[4]) =
            *reinterpret_cast<const float4*>(&Pl2[1][il * DD + tj * 8 + 4]);
        #pragma unroll
        for (int a = 0; a < 8; ++a)
          #pragma unroll
          for (int b = 0; b < 8; ++b) {
            y0[a][b] = fmaf(xv[a], p0[b], y0[a][b]);
            y1[a][b] = fmaf(xv[a], p1[b], y1[a][b]);
          }
      }
    }

    // epilogue: q'[n] = sum_j (x[n,j]-mu_j) * (y[n,j]-wv_j), partial over tj's 8 j
    float s0[8], s1[8];
    #pragma unroll
    for (int a = 0; a < 8; ++a) { s0[a] = 0.0f; s1[a] = 0.0f; }
    #pragma unroll
    for (int b = 0; b < 8; ++b) {
      const int j = tj * 8 + b;
      const int swj = ((j >> 2) & 15) << 2;
      float dv[8];
      *reinterpret_cast<float4*>(&dv[0]) =
          *reinterpret_cast<const float4*>(&XT[j][(tn * 8) ^ swj]);
      *reinterpret_cast<float4*>(&dv[4]) =
          *reinterpret_cast<const float4*>(&XT[j][(tn * 8 + 4) ^ swj]);
      const float m1 = muw[0][0][j], w1 = muw[0][1][j];
      const float m2 = muw[1][0][j], w2 = muw[1][1][j];
      #pragma unroll
      for (int a = 0; a < 8; ++a) {
        s0[a] = fmaf(dv[a] - m1, y0[a][b] - w1, s0[a]);
        s1[a] = fmaf(dv[a] - m2, y1[a][b] - w2, s1[a]);
      }
    }

    float* qred = &Pl2[0][0];  // 2048 floats; Pl2 dead until next pair
    __syncthreads();           // all compute reads of Pl2 done
    #pragma unroll
    for (int a = 0; a < 8; a += 4)
      *reinterpret_cast<float4*>(&qred[tj * 64 + tn * 8 + a]) =
          *reinterpret_cast<const float4*>(&s0[a]);
    __syncthreads();
    if (tid < 64) {
      float qa = 0.f, qb = 0.f, qc = 0.f, qd = 0.f;
      #pragma unroll
      for (int t = 0; t < 32; t += 4) {
        qa += qred[(t + 0) * 64 + tid];
        qb += qred[(t + 1) * 64 + tid];
        qc += qred[(t + 2) * 64 + tid];
        qd += qred[(t + 3) * 64 + tid];
      }
      lpb[2 * kp][tid] = fmaf(0.5f, (qa + qb) + (qc + qd), cA[k1]);
    }
    __syncthreads();
    #pragma unroll
    for (int a = 0; a < 8; a += 4)
      *reinterpret_cast<float4*>(&qred[tj * 64 + tn * 8 + a]) =
          *reinterpret_cast<const float4*>(&s1[a]);
    __syncthreads();
    if (tid < 64) {
      float qa = 0.f, qb = 0.f, qc = 0.f, qd = 0.f;
      #pragma unroll
      for (int t = 0; t < 32; t += 4) {
        qa += qred[(t + 0) * 64 + tid];
        qb += qred[(t + 1) * 64 + tid];
        qc += qred[(t + 2) * 64 + tid];
        qd += qred[(t + 3) * 64 + tid];
      }
      lpb[2 * kp + 1][tid] = fmaf(0.5f, (qa + qb) + (qc + qd), cA[k2]);
    }
  }

  // coalesced lp flush: 2 float4 per point row (8 k values)
  __syncthreads();
  if (tid < 128) {
    const int n = tid >> 1;
    const int h = (tid & 1) * 4;
    float4 o = {lpb[h + 0][n], lpb[h + 1][n], lpb[h + 2][n], lpb[h + 3][n]};
    *reinterpret_cast<float4*>(&lp[(size_t)(n0 + n) * KC + k0 + h]) = o;
  }
}

// ---------------- Kernel 3: row softmax over K+1 = 65 entries -----------------
__global__ __launch_bounds__(64) void softmax_kernel(
    const float* __restrict__ lp, const int* __restrict__ n_points_p,
    float* __restrict__ out)
{
  const int n = blockIdx.x;
  const int l = threadIdx.x;
  const float denom = (float)(*n_points_p) + 1.0f;
  const float log_new = -logf(denom);  // log(ALPHA/denom), ALPHA=1

  float v = lp[(size_t)n * KC + l];
  float m = v;
  #pragma unroll
  for (int off = 32; off > 0; off >>= 1) m = fmaxf(m, __shfl_xor(m, off, 64));
  m = fmaxf(m, log_new);

  float e = expf(v - m);
  float s = e;
  #pragma unroll
  for (int off = 32; off > 0; off >>= 1) s += __shfl_xor(s, off, 64);
  float enew = expf(log_new - m);
  s += enew;

  out[(size_t)n * (KC + 1) + l] = e / s;
  if (l == 0) out[(size_t)n * (KC + 1) + KC] = enew / s;
}

extern "C" void kernel_launch(void* const* d_in, const int* in_sizes, int n_in,
                              void* d_out, int out_size, void* d_ws, size_t ws_size,
                              hipStream_t stream)
{
  const float* x       = (const float*)d_in[0];  // [N, D]
  const float* means   = (const float*)d_in[1];  // [K, D]
  const float* covs    = (const float*)d_in[2];  // [K, D, D]
  const float* counts  = (const float*)d_in[3];  // [K]
  const int*   n_points = (const int*)d_in[4];   // scalar

  float* S   = (float*)d_ws;                      // K*D*D
  float* cA  = S + (size_t)KC * DD * DD;          // K
  float* ldp = cA + KC;                           // 4*K
  float* lp  = ldp + 4 * KC;                      // N*K
  float* Plbuf = lp;  // alias: Plbuf (K*64*64 = N*K floats) used only during
                      // sweep; lp written only by quad afterwards.
  float* out = (float*)d_out;                     // [N, K+1]
  // wv = S_k*mu_k staged in the out buffer (64KB of 1MB); quad reads it before
  // softmax overwrites out — stream-ordered, safe.
  float* wv = out;

  for (int bs = 0; bs < 4; ++bs) {
    pivot_kernel<<<dim3(KC, 5), 512, 0, stream>>>(covs, S, Plbuf, ldp, bs);
    update_kernel<<<dim3(KC, 3), 512, 0, stream>>>(covs, S, Plbuf, bs);
  }
  pivot_kernel<<<dim3(KC, 5), 512, 0, stream>>>(covs, S, Plbuf, ldp, 4);
  w_kernel<<<KC, 256, 0, stream>>>(S, means, counts, n_points, ldp, cA, wv);
  quad_kernel<<<dim3(NPTS / NT, KC / KG), 256, 0, stream>>>(x, means, S, cA, wv, lp);
  softmax_kernel<<<NPTS, 64, 0, stream>>>(lp, n_points, out);
}

// Round 6
// 775.412 us; speedup vs baseline: 9.0771x; 1.0019x over previous
//
#include <hip/hip_runtime.h>
#include <math.h>

// StreamingDPM: probs = softmax([ -0.5*(D log2pi + logdet_k + quad_nk) + log_prior_k | log_new ])
// N=4096 D=256 K=64, out [N, K+1] fp32.
//
// ws layout (floats):
//   S    : K*D*D  (sweep result; holds -Sigma^{-1} after all steps)
//   cA   : K      (log_prior_k - 0.5*(D log2pi + logdet_k))
//   ldp  : 4*K    (per-block-step logdet partials)
//   lp   : N*K    (log-probs before softmax; ALIASED as Plbuf during sweep)
// wv (= S_k * mu_k, [K][D]) lives in the OUTPUT buffer temporarily (quad reads
// it before softmax overwrites out; stream-ordered, safe).
//
// Sweep schedule (per block step bs): pivot_kernel grid (K,5):
//   by<4  : deferred J-column writeback of step bs-1 (parallel, 64 rows each)
//   by==4 : register-resident sweep of the 64x64 pivot block (1 barrier/pivot)
// then update_kernel (K,3): trailing update of the 3 non-J column slices.
// J-col writes are deferred one launch so no block writes S[:,J] while another
// reads C = S[:,J]. Step 0 reads covs directly.

#define DD 256
#define KC 64
#define NPTS 4096
#define NT 64
#define BB 64          // sweep block size
#define KG 8           // clusters per quad block (processed as 4 pairs)
#define CH 4           // S chunk rows staged per quad step (per cluster)
#define NCH (DD / CH)  // 64 chunks

// ---------------- Kernel 1a: pivot sweep + deferred J-col writeback ----------
__global__ __launch_bounds__(512) void pivot_kernel(
    const float* __restrict__ covs, float* __restrict__ S,
    float* __restrict__ Plbuf, float* __restrict__ ldp, int bs)
{
  const int k = blockIdx.x;
  const int by = blockIdx.y;
  const int tid = threadIdx.x;
  float* Pb = Plbuf + (size_t)k * BB * BB;

  __shared__ __align__(16) float Tl[BB][BB + 4];
  __shared__ __align__(16) float pivc[2][BB];
  __shared__ __align__(16) float pivr[2][BB];

  if (by < 4) {
    // ---- deferred write of step bs-1's J columns (rows r0..r0+63):
    //  M[J,J] = -P^{-1} = Pb ;  M[I,J] = C*P^{-1} = -(C*Pb)
    if (bs == 0) return;
    const int j0p = (bs - 1) * BB;
    const int r0 = by * BB;
    const float* src = ((bs == 1) ? covs : (const float*)S) + (size_t)k * DD * DD;
    float* dst = S + (size_t)k * DD * DD;

    const int rr = tid >> 3;         // 0..63
    const int cc = (tid & 7) * 8;    // 0..56
    *reinterpret_cast<float4*>(&Tl[rr][cc]) =
        *reinterpret_cast<const float4*>(&Pb[rr * BB + cc]);
    *reinterpret_cast<float4*>(&Tl[rr][cc + 4]) =
        *reinterpret_cast<const float4*>(&Pb[rr * BB + cc + 4]);
    __syncthreads();

    const int r = r0 + rr;
    if (r0 == j0p) {
      // rows in J: direct copy of -P^{-1}
      *reinterpret_cast<float4*>(&dst[(size_t)r * DD + j0p + cc]) =
          *reinterpret_cast<const float4*>(&Tl[rr][cc]);
      *reinterpret_cast<float4*>(&dst[(size_t)r * DD + j0p + cc + 4]) =
          *reinterpret_cast<const float4*>(&Tl[rr][cc + 4]);
    } else {
      float Crow[BB];
      #pragma unroll
      for (int p = 0; p < BB; p += 4) {
        float4 cv = *reinterpret_cast<const float4*>(&src[(size_t)r * DD + j0p + p]);
        Crow[p] = cv.x; Crow[p + 1] = cv.y; Crow[p + 2] = cv.z; Crow[p + 3] = cv.w;
      }
      float acc[8] = {0.f, 0.f, 0.f, 0.f, 0.f, 0.f, 0.f, 0.f};
      #pragma unroll
      for (int p = 0; p < BB; ++p) {
        float4 t0 = *reinterpret_cast<const float4*>(&Tl[p][cc]);
        float4 t1 = *reinterpret_cast<const float4*>(&Tl[p][cc + 4]);
        acc[0] = fmaf(Crow[p], t0.x, acc[0]);
        acc[1] = fmaf(Crow[p], t0.y, acc[1]);
        acc[2] = fmaf(Crow[p], t0.z, acc[2]);
        acc[3] = fmaf(Crow[p], t0.w, acc[3]);
        acc[4] = fmaf(Crow[p], t1.x, acc[4]);
        acc[5] = fmaf(Crow[p], t1.y, acc[5]);
        acc[6] = fmaf(Crow[p], t1.z, acc[6]);
        acc[7] = fmaf(Crow[p], t1.w, acc[7]);
      }
      float4 o0 = {-acc[0], -acc[1], -acc[2], -acc[3]};
      float4 o1 = {-acc[4], -acc[5], -acc[6], -acc[7]};
      *reinterpret_cast<float4*>(&dst[(size_t)r * DD + j0p + cc]) = o0;
      *reinterpret_cast<float4*>(&dst[(size_t)r * DD + j0p + cc + 4]) = o1;
    }
    return;
  }

  if (bs == 4) return;  // flush launch: defer blocks only

  // ---- register-resident sweep of P = S[J,J] (step 0: from covs).
  // Thread owns row pr, cols pc..pc+7 in VGPRs for all 64 pivots; only the
  // pivot row/col is exchanged via double-buffered LDS. 1 barrier per pivot.
  const int j0 = bs * BB;
  const float* psrc = ((bs == 0) ? covs : (const float*)S) + (size_t)k * DD * DD;
  const int pr = tid >> 3;
  const int pc = (tid & 7) * 8;

  float v[8];
  {
    float4 a4 = *reinterpret_cast<const float4*>(&psrc[(size_t)(j0 + pr) * DD + j0 + pc]);
    float4 b4 = *reinterpret_cast<const float4*>(&psrc[(size_t)(j0 + pr) * DD + j0 + pc + 4]);
    v[0] = a4.x; v[1] = a4.y; v[2] = a4.z; v[3] = a4.w;
    v[4] = b4.x; v[5] = b4.y; v[6] = b4.z; v[7] = b4.w;
  }
  if (pc == 0) pivc[0][pr] = v[0];
  if (pr == 0) {
    #pragma unroll
    for (int e = 0; e < 8; ++e) pivr[0][pc + e] = v[e];
  }
  __syncthreads();

  float ld = 0.0f;
  #pragma unroll 1
  for (int p = 0; p < BB; ++p) {
    const int cur = p & 1, nxt = cur ^ 1;
    const float d = pivc[cur][p];
    const float inv_d = 1.0f / d;
    if (tid == 0) ld += logf(d);
    const float cr = pivc[cur][pr];
    float rw[8];
    *reinterpret_cast<float4*>(&rw[0]) = *reinterpret_cast<const float4*>(&pivr[cur][pc]);
    *reinterpret_cast<float4*>(&rw[4]) = *reinterpret_cast<const float4*>(&pivr[cur][pc + 4]);
    #pragma unroll
    for (int e = 0; e < 8; ++e) {
      float ge = fmaf(-inv_d * cr, rw[e], v[e]);         // general update
      if (pr == p)     ge = rw[e] * inv_d;               // pivot row
      if (pc + e == p) ge = (pr == p) ? -inv_d : cr * inv_d;  // pivot col/diag
      v[e] = ge;
    }
    if (p < BB - 1) {
      if (pr == p + 1) {
        #pragma unroll
        for (int e = 0; e < 8; ++e) pivr[nxt][pc + e] = v[e];
      }
      if (pc <= p + 1 && p + 1 < pc + 8) pivc[nxt][pr] = v[p + 1 - pc];
    }
    __syncthreads();
  }

  // store -P^{-1} for the update/deferred kernels (coalesced)
  float4 s0 = {v[0], v[1], v[2], v[3]};
  float4 s1 = {v[4], v[5], v[6], v[7]};
  *reinterpret_cast<float4*>(&Pb[pr * BB + pc]) = s0;
  *reinterpret_cast<float4*>(&Pb[pr * BB + pc + 4]) = s1;
  if (tid == 0) ldp[bs * KC + k] = ld;
}

// ---------------- Kernel 1b: trailing update of one non-J column slice ------
__global__ __launch_bounds__(512) void update_kernel(
    const float* __restrict__ covs, float* __restrict__ S,
    const float* __restrict__ Plbuf, int bs)
{
  const int k = blockIdx.x;
  const int si = blockIdx.y;
  const int t = si + (si >= bs ? 1 : 0);
  const int c0 = t * BB;
  const int j0 = bs * BB;
  const int tid = threadIdx.x;
  const float* src = ((bs == 0) ? covs : (const float*)S) + (size_t)k * DD * DD;
  float* dst = S + (size_t)k * DD * DD;

  __shared__ __align__(16) float Pl[BB][BB + 4];
  __shared__ __align__(16) float SJ[BB][BB + 4];
  __shared__ __align__(16) float Tl[BB][BB + 4];

  const float* Pb = Plbuf + (size_t)k * BB * BB;
  #pragma unroll
  for (int q = 0; q < 8; ++q) {
    int e = q * 512 + tid;
    int r = e >> 6, c = e & 63;
    Pl[r][c] = Pb[e];
    SJ[r][c] = src[(size_t)(j0 + r) * DD + c0 + c];
  }
  __syncthreads();

  // ---- T' = Pl * SJ  (thread: col c, 8 rows)
  {
    const int c = tid & 63;
    const int rg = (tid >> 6) * 8;
    float tv[8];
    #pragma unroll
    for (int r = 0; r < 8; ++r) tv[r] = 0.0f;
    for (int p = 0; p < BB; p += 4) {
      float s0 = SJ[p][c], s1 = SJ[p + 1][c], s2 = SJ[p + 2][c], s3 = SJ[p + 3][c];
      #pragma unroll
      for (int r = 0; r < 8; ++r) {
        float4 pv = *reinterpret_cast<const float4*>(&Pl[rg + r][p]);
        tv[r] = fmaf(pv.x, s0, fmaf(pv.y, s1, fmaf(pv.z, s2, fmaf(pv.w, s3, tv[r]))));
      }
    }
    #pragma unroll
    for (int r = 0; r < 8; ++r) Tl[rg + r][c] = tv[r];
  }
  __syncthreads();

  // ---- apply to this column slice (thread: row r, 32 cols)
  const int r = tid & 255;
  const int h = (tid >> 8) * 32;
  const bool inJ = (r >= j0) && (r < j0 + BB);  // wave-uniform
  if (inJ) {
    #pragma unroll
    for (int c = 0; c < 32; c += 4) {
      float4 tv4 = *reinterpret_cast<const float4*>(&Tl[r - j0][h + c]);
      float4 o = {-tv4.x, -tv4.y, -tv4.z, -tv4.w};
      *reinterpret_cast<float4*>(&dst[(size_t)r * DD + c0 + h + c]) = o;
    }
  } else {
    float Crow[BB];
    #pragma unroll
    for (int p = 0; p < BB; p += 4) {
      float4 cv = *reinterpret_cast<const float4*>(&src[(size_t)r * DD + j0 + p]);
      Crow[p] = cv.x; Crow[p + 1] = cv.y; Crow[p + 2] = cv.z; Crow[p + 3] = cv.w;
    }
    #pragma unroll
    for (int c = 0; c < 32; c += 4) {
      float4 acc = *reinterpret_cast<const float4*>(&src[(size_t)r * DD + c0 + h + c]);
      #pragma unroll
      for (int p = 0; p < BB; ++p) {
        float4 tv4 = *reinterpret_cast<const float4*>(&Tl[p][h + c]);
        acc.x = fmaf(Crow[p], tv4.x, acc.x);
        acc.y = fmaf(Crow[p], tv4.y, acc.y);
        acc.z = fmaf(Crow[p], tv4.z, acc.z);
        acc.w = fmaf(Crow[p], tv4.w, acc.w);
      }
      *reinterpret_cast<float4*>(&dst[(size_t)r * DD + c0 + h + c]) = acc;
    }
  }
}

// ---------------- Kernel 1c: wv_k = S_k * mu_k ; cA assembly -----------------
__global__ __launch_bounds__(256) void w_kernel(
    const float* __restrict__ S, const float* __restrict__ means,
    const float* __restrict__ counts, const int* __restrict__ n_points_p,
    const float* __restrict__ ldp, float* __restrict__ cA,
    float* __restrict__ wv)
{
  const int k = blockIdx.x;
  const int tid = threadIdx.x;
  if (tid == 0) {
    float denom = (float)(*n_points_p) + 1.0f;  // ALPHA = 1
    float ld = ldp[k] + ldp[KC + k] + ldp[2 * KC + k] + ldp[3 * KC + k];
    // D*log(2*pi) = 256 * 1.8378770664093453
    cA[k] = logf(counts[k] / denom) - 0.5f * (470.49652900079047f + ld);
  }
  const float* Sk = S + (size_t)k * DD * DD;
  __shared__ float mus[DD];
  mus[tid] = means[(size_t)k * DD + tid];
  __syncthreads();
  float a0 = 0.f, a1 = 0.f, a2 = 0.f, a3 = 0.f;
  for (int j = 0; j < DD; j += 4) {
    a0 = fmaf(Sk[(size_t)(j + 0) * DD + tid], mus[j + 0], a0);
    a1 = fmaf(Sk[(size_t)(j + 1) * DD + tid], mus[j + 1], a1);
    a2 = fmaf(Sk[(size_t)(j + 2) * DD + tid], mus[j + 2], a2);
    a3 = fmaf(Sk[(size_t)(j + 3) * DD + tid], mus[j + 3], a3);
  }
  wv[(size_t)k * DD + tid] = (a0 + a1) + (a2 + a3);
}

// ---------------- Kernel 2: quad via mean-folded GEMM ------------------------
// dev^T S dev = sum_j (x_j - mu_j) * ((X*S)_nj - wv_j)   (S symmetric).
// 8n x 8j register tile, 2 clusters at once (XT reads shared): per il step
// 6 ds_read_b128 feed 128 FMAs. Needs ~190 live VGPRs: amdgpu_waves_per_eu(2,2)
// pins the allocator to the 256-VGPR budget (2 waves/EU = what LDS allows
// anyway) — with __launch_bounds__(256,2) it targeted 4 waves/EU, capped at
// 128 VGPRs and spilled ~60 floats/thread (WRITE_SIZE 125 MB of scratch, r5).
// KG=8 clusters per block as 4 pairs. S streamed in CH=4-row chunks,
// register-prefetched. LDS = 64+8+4+2 = 78 KB -> 2 blocks/CU.
__global__
__attribute__((amdgpu_flat_work_group_size(256, 256), amdgpu_waves_per_eu(2, 2)))
void quad_kernel(
    const float* __restrict__ X, const float* __restrict__ means,
    const float* __restrict__ S, const float* __restrict__ cA,
    const float* __restrict__ wv, float* __restrict__ lp)
{
  __shared__ __align__(16) float XT[DD][NT];      // (i,r) at XT[i][r ^ (((i>>2)&15)<<2)]
  __shared__ __align__(16) float Pl2[2][CH * DD]; // S chunks (2 clusters); qred alias
  __shared__ __align__(16) float muw[2][2][DD];   // per-pair {mu, wv} x 2 clusters
  __shared__ __align__(16) float lpb[KG][NT];     // results, flushed coalesced

  const int tid = threadIdx.x;
  const int n0 = blockIdx.x * NT;
  const int k0 = blockIdx.y * KG;

  // stage X tile transposed + swizzled (once per block)
  #pragma unroll
  for (int q = 0; q < 16; ++q) {
    int f = q * 1024 + tid * 4;
    int r = f >> 8;
    int c = f & 255;
    float4 xv = *reinterpret_cast<const float4*>(X + (size_t)(n0 + r) * DD + c);
    int rs = r ^ (((c >> 2) & 15) << 2);
    XT[c + 0][rs] = xv.x;
    XT[c + 1][rs] = xv.y;
    XT[c + 2][rs] = xv.z;
    XT[c + 3][rs] = xv.w;
  }

  const int tn = tid & 7;    // n sub-tile: rows tn*8 .. +7
  const int tj = tid >> 3;   // j sub-tile: cols tj*8 .. +7

  #pragma unroll 1
  for (int kp = 0; kp < KG / 2; ++kp) {
    const int k1 = k0 + kp * 2;
    const int k2 = k1 + 1;
    const float* S1 = S + (size_t)k1 * DD * DD;
    const float* S2 = S + (size_t)k2 * DD * DD;

    __syncthreads();  // prev pair's qred/muw readers done; XT staged (kp==0)
    muw[0][0][tid] = means[(size_t)k1 * DD + tid];
    muw[0][1][tid] = wv[(size_t)k1 * DD + tid];
    muw[1][0][tid] = means[(size_t)k2 * DD + tid];
    muw[1][1][tid] = wv[(size_t)k2 * DD + tid];

    // prologue: chunk 0 of both clusters -> registers
    float4 pre0 = *reinterpret_cast<const float4*>(S1 + tid * 4);
    float4 pre1 = *reinterpret_cast<const float4*>(S2 + tid * 4);

    float y0[8][8], y1[8][8];
    #pragma unroll
    for (int a = 0; a < 8; ++a)
      #pragma unroll
      for (int b = 0; b < 8; ++b) { y0[a][b] = 0.0f; y1[a][b] = 0.0f; }

    #pragma unroll 1
    for (int ct = 0; ct < NCH; ++ct) {
      __syncthreads();  // Pl2 free (prev chunk consumed); muw/XT visible
      *reinterpret_cast<float4*>(&Pl2[0][tid * 4]) = pre0;
      *reinterpret_cast<float4*>(&Pl2[1][tid * 4]) = pre1;
      if (ct < NCH - 1) {  // next chunk's loads stay in flight across compute
        pre0 = *reinterpret_cast<const float4*>(S1 + (size_t)(ct + 1) * CH * DD + tid * 4);
        pre1 = *reinterpret_cast<const float4*>(S2 + (size_t)(ct + 1) * CH * DD + tid * 4);
      }
      __syncthreads();  // Pl2 ready

      #pragma unroll
      for (int il = 0; il < CH; ++il) {
        const int i = ct * CH + il;
        const int sw = ((i >> 2) & 15) << 2;
        float xv[8], p0[8], p1[8];
        *reinterpret_cast<float4*>(&xv[0]) =
            *reinterpret_cast<const float4*>(&XT[i][(tn * 8) ^ sw]);
        *reinterpret_cast<float4*>(&xv[4]) =
            *reinterpret_cast<const float4*>(&XT[i][(tn * 8 + 4) ^ sw]);
        *reinterpret_cast<float4*>(&p0[0]) =
            *reinterpret_cast<const float4*>(&Pl2[0][il * DD + tj * 8]);
        *reinterpret_cast<float4*>(&p0[4]) =
            *reinterpret_cast<const float4*>(&Pl2[0][il * DD + tj * 8 + 4]);
        *reinterpret_cast<float4*>(&p1[0]) =
            *reinterpret_cast<const float4*>(&Pl2[1][il * DD + tj * 8]);
        *reinterpret_cast<float4*>(&p1[4]) =
            *reinterpret_cast<const float4*>(&Pl2[1][il * DD + tj * 8 + 4]);
        #pragma unroll
        for (int a = 0; a < 8; ++a)
          #pragma unroll
          for (int b = 0; b < 8; ++b) {
            y0[a][b] = fmaf(xv[a], p0[b], y0[a][b]);
            y1[a][b] = fmaf(xv[a], p1[b], y1[a][b]);
          }
      }
    }

    // epilogue: q'[n] = sum_j (x[n,j]-mu_j) * (y[n,j]-wv_j), partial over tj's 8 j
    float s0[8], s1[8];
    #pragma unroll
    for (int a = 0; a < 8; ++a) { s0[a] = 0.0f; s1[a] = 0.0f; }
    #pragma unroll
    for (int b = 0; b < 8; ++b) {
      const int j = tj * 8 + b;
      const int swj = ((j >> 2) & 15) << 2;
      float dv[8];
      *reinterpret_cast<float4*>(&dv[0]) =
          *reinterpret_cast<const float4*>(&XT[j][(tn * 8) ^ swj]);
      *reinterpret_cast<float4*>(&dv[4]) =
          *reinterpret_cast<const float4*>(&XT[j][(tn * 8 + 4) ^ swj]);
      const float m1 = muw[0][0][j], w1 = muw[0][1][j];
      const float m2 = muw[1][0][j], w2 = muw[1][1][j];
      #pragma unroll
      for (int a = 0; a < 8; ++a) {
        s0[a] = fmaf(dv[a] - m1, y0[a][b] - w1, s0[a]);
        s1[a] = fmaf(dv[a] - m2, y1[a][b] - w2, s1[a]);
      }
    }

    float* qred = &Pl2[0][0];  // 2048 floats; Pl2 dead until next pair
    __syncthreads();           // all compute reads of Pl2 done
    #pragma unroll
    for (int a = 0; a < 8; a += 4)
      *reinterpret_cast<float4*>(&qred[tj * 64 + tn * 8 + a]) =
          *reinterpret_cast<const float4*>(&s0[a]);
    __syncthreads();
    if (tid < 64) {
      float qa = 0.f, qb = 0.f, qc = 0.f, qd = 0.f;
      #pragma unroll
      for (int t = 0; t < 32; t += 4) {
        qa += qred[(t + 0) * 64 + tid];
        qb += qred[(t + 1) * 64 + tid];
        qc += qred[(t + 2) * 64 + tid];
        qd += qred[(t + 3) * 64 + tid];
      }
      lpb[2 * kp][tid] = fmaf(0.5f, (qa + qb) + (qc + qd), cA[k1]);
    }
    __syncthreads();
    #pragma unroll
    for (int a = 0; a < 8; a += 4)
      *reinterpret_cast<float4*>(&qred[tj * 64 + tn * 8 + a]) =
          *reinterpret_cast<const float4*>(&s1[a]);
    __syncthreads();
    if (tid < 64) {
      float qa = 0.f, qb = 0.f, qc = 0.f, qd = 0.f;
      #pragma unroll
      for (int t = 0; t < 32; t += 4) {
        qa += qred[(t + 0) * 64 + tid];
        qb += qred[(t + 1) * 64 + tid];
        qc += qred[(t + 2) * 64 + tid];
        qd += qred[(t + 3) * 64 + tid];
      }
      lpb[2 * kp + 1][tid] = fmaf(0.5f, (qa + qb) + (qc + qd), cA[k2]);
    }
  }

  // coalesced lp flush: 2 float4 per point row (8 k values)
  __syncthreads();
  if (tid < 128) {
    const int n = tid >> 1;
    const int h = (tid & 1) * 4;
    float4 o = {lpb[h + 0][n], lpb[h + 1][n], lpb[h + 2][n], lpb[h + 3][n]};
    *reinterpret_cast<float4*>(&lp[(size_t)(n0 + n) * KC + k0 + h]) = o;
  }
}

// ---------------- Kernel 3: row softmax over K+1 = 65 entries -----------------
__global__ __launch_bounds__(64) void softmax_kernel(
    const float* __restrict__ lp, const int* __restrict__ n_points_p,
    float* __restrict__ out)
{
  const int n = blockIdx.x;
  const int l = threadIdx.x;
  const float denom = (float)(*n_points_p) + 1.0f;
  const float log_new = -logf(denom);  // log(ALPHA/denom), ALPHA=1

  float v = lp[(size_t)n * KC + l];
  float m = v;
  #pragma unroll
  for (int off = 32; off > 0; off >>= 1) m = fmaxf(m, __shfl_xor(m, off, 64));
  m = fmaxf(m, log_new);

  float e = expf(v - m);
  float s = e;
  #pragma unroll
  for (int off = 32; off > 0; off >>= 1) s += __shfl_xor(s, off, 64);
  float enew = expf(log_new - m);
  s += enew;

  out[(size_t)n * (KC + 1) + l] = e / s;
  if (l == 0) out[(size_t)n * (KC + 1) + KC] = enew / s;
}

extern "C" void kernel_launch(void* const* d_in, const int* in_sizes, int n_in,
                              void* d_out, int out_size, void* d_ws, size_t ws_size,
                              hipStream_t stream)
{
  const float* x       = (const float*)d_in[0];  // [N, D]
  const float* means   = (const float*)d_in[1];  // [K, D]
  const float* covs    = (const float*)d_in[2];  // [K, D, D]
  const float* counts  = (const float*)d_in[3];  // [K]
  const int*   n_points = (const int*)d_in[4];   // scalar

  float* S   = (float*)d_ws;                      // K*D*D
  float* cA  = S + (size_t)KC * DD * DD;          // K
  float* ldp = cA + KC;                           // 4*K
  float* lp  = ldp + 4 * KC;                      // N*K
  float* Plbuf = lp;  // alias: Plbuf (K*64*64 = N*K floats) used only during
                      // sweep; lp written only by quad afterwards.
  float* out = (float*)d_out;                     // [N, K+1]
  // wv = S_k*mu_k staged in the out buffer (64KB of 1MB); quad reads it before
  // softmax overwrites out — stream-ordered, safe.
  float* wv = out;

  for (int bs = 0; bs < 4; ++bs) {
    pivot_kernel<<<dim3(KC, 5), 512, 0, stream>>>(covs, S, Plbuf, ldp, bs);
    update_kernel<<<dim3(KC, 3), 512, 0, stream>>>(covs, S, Plbuf, bs);
  }
  pivot_kernel<<<dim3(KC, 5), 512, 0, stream>>>(covs, S, Plbuf, ldp, 4);
  w_kernel<<<KC, 256, 0, stream>>>(S, means, counts, n_points, ldp, cA, wv);
  quad_kernel<<<dim3(NPTS / NT, KC / KG), 256, 0, stream>>>(x, means, S, cA, wv, lp);
  softmax_kernel<<<NPTS, 64, 0, stream>>>(lp, n_points, out);
}

// Round 7
// 648.234 us; speedup vs baseline: 10.8579x; 1.1962x over previous
//
#include <hip/hip_runtime.h>
#include <math.h>

// StreamingDPM: probs = softmax([ -0.5*(D log2pi + logdet_k + quad_nk) + log_prior_k | log_new ])
// N=4096 D=256 K=64, out [N, K+1] fp32.
//
// ws layout (floats):
//   S    : K*D*D  (sweep result; holds -Sigma^{-1} after all steps)
//   cA   : K      (log_prior_k - 0.5*(D log2pi + logdet_k))
//   ldp  : 4*K    (per-block-step logdet partials)
//   lp   : N*K    (log-probs before softmax; ALIASED as Plbuf during sweep)
// wv (= S_k * mu_k, [K][D]) lives in the OUTPUT buffer temporarily (quad reads
// it before softmax overwrites out; stream-ordered, safe).
//
// Sweep schedule (per block step bs): pivot_kernel grid (K,5):
//   by<4  : deferred J-column writeback of step bs-1 (parallel, 64 rows each)
//   by==4 : register-resident sweep of the 64x64 pivot block (1 barrier/pivot)
// then update_kernel (K,3): trailing update of the 3 non-J column slices.
// J-col writes are deferred one launch so no block writes S[:,J] while another
// reads C = S[:,J]. Step 0 reads covs directly.

#define DD 256
#define KC 64
#define NPTS 4096
#define NT 64
#define BB 64          // sweep block size
#define KG 4           // clusters per quad block
#define CH 8           // S chunk rows staged per quad step
#define NCH (DD / CH)  // 32 chunks

// ---------------- Kernel 1a: pivot sweep + deferred J-col writeback ----------
__global__ __launch_bounds__(512) void pivot_kernel(
    const float* __restrict__ covs, float* __restrict__ S,
    float* __restrict__ Plbuf, float* __restrict__ ldp, int bs)
{
  const int k = blockIdx.x;
  const int by = blockIdx.y;
  const int tid = threadIdx.x;
  float* Pb = Plbuf + (size_t)k * BB * BB;

  __shared__ __align__(16) float Tl[BB][BB + 4];
  __shared__ __align__(16) float pivc[2][BB];
  __shared__ __align__(16) float pivr[2][BB];

  if (by < 4) {
    // ---- deferred write of step bs-1's J columns (rows r0..r0+63):
    //  M[J,J] = -P^{-1} = Pb ;  M[I,J] = C*P^{-1} = -(C*Pb)
    if (bs == 0) return;
    const int j0p = (bs - 1) * BB;
    const int r0 = by * BB;
    const float* src = ((bs == 1) ? covs : (const float*)S) + (size_t)k * DD * DD;
    float* dst = S + (size_t)k * DD * DD;

    const int rr = tid >> 3;         // 0..63
    const int cc = (tid & 7) * 8;    // 0..56
    *reinterpret_cast<float4*>(&Tl[rr][cc]) =
        *reinterpret_cast<const float4*>(&Pb[rr * BB + cc]);
    *reinterpret_cast<float4*>(&Tl[rr][cc + 4]) =
        *reinterpret_cast<const float4*>(&Pb[rr * BB + cc + 4]);
    __syncthreads();

    const int r = r0 + rr;
    if (r0 == j0p) {
      // rows in J: direct copy of -P^{-1}
      *reinterpret_cast<float4*>(&dst[(size_t)r * DD + j0p + cc]) =
          *reinterpret_cast<const float4*>(&Tl[rr][cc]);
      *reinterpret_cast<float4*>(&dst[(size_t)r * DD + j0p + cc + 4]) =
          *reinterpret_cast<const float4*>(&Tl[rr][cc + 4]);
    } else {
      float Crow[BB];
      #pragma unroll
      for (int p = 0; p < BB; p += 4) {
        float4 cv = *reinterpret_cast<const float4*>(&src[(size_t)r * DD + j0p + p]);
        Crow[p] = cv.x; Crow[p + 1] = cv.y; Crow[p + 2] = cv.z; Crow[p + 3] = cv.w;
      }
      float acc[8] = {0.f, 0.f, 0.f, 0.f, 0.f, 0.f, 0.f, 0.f};
      #pragma unroll
      for (int p = 0; p < BB; ++p) {
        float4 t0 = *reinterpret_cast<const float4*>(&Tl[p][cc]);
        float4 t1 = *reinterpret_cast<const float4*>(&Tl[p][cc + 4]);
        acc[0] = fmaf(Crow[p], t0.x, acc[0]);
        acc[1] = fmaf(Crow[p], t0.y, acc[1]);
        acc[2] = fmaf(Crow[p], t0.z, acc[2]);
        acc[3] = fmaf(Crow[p], t0.w, acc[3]);
        acc[4] = fmaf(Crow[p], t1.x, acc[4]);
        acc[5] = fmaf(Crow[p], t1.y, acc[5]);
        acc[6] = fmaf(Crow[p], t1.z, acc[6]);
        acc[7] = fmaf(Crow[p], t1.w, acc[7]);
      }
      float4 o0 = {-acc[0], -acc[1], -acc[2], -acc[3]};
      float4 o1 = {-acc[4], -acc[5], -acc[6], -acc[7]};
      *reinterpret_cast<float4*>(&dst[(size_t)r * DD + j0p + cc]) = o0;
      *reinterpret_cast<float4*>(&dst[(size_t)r * DD + j0p + cc + 4]) = o1;
    }
    return;
  }

  if (bs == 4) return;  // flush launch: defer blocks only

  // ---- register-resident sweep of P = S[J,J] (step 0: from covs).
  // Thread owns row pr, cols pc..pc+7 in VGPRs for all 64 pivots; only the
  // pivot row/col is exchanged via double-buffered LDS. 1 barrier per pivot.
  const int j0 = bs * BB;
  const float* psrc = ((bs == 0) ? covs : (const float*)S) + (size_t)k * DD * DD;
  const int pr = tid >> 3;
  const int pc = (tid & 7) * 8;

  float v[8];
  {
    float4 a4 = *reinterpret_cast<const float4*>(&psrc[(size_t)(j0 + pr) * DD + j0 + pc]);
    float4 b4 = *reinterpret_cast<const float4*>(&psrc[(size_t)(j0 + pr) * DD + j0 + pc + 4]);
    v[0] = a4.x; v[1] = a4.y; v[2] = a4.z; v[3] = a4.w;
    v[4] = b4.x; v[5] = b4.y; v[6] = b4.z; v[7] = b4.w;
  }
  if (pc == 0) pivc[0][pr] = v[0];
  if (pr == 0) {
    #pragma unroll
    for (int e = 0; e < 8; ++e) pivr[0][pc + e] = v[e];
  }
  __syncthreads();

  float ld = 0.0f;
  #pragma unroll 1
  for (int p = 0; p < BB; ++p) {
    const int cur = p & 1, nxt = cur ^ 1;
    const float d = pivc[cur][p];
    const float inv_d = 1.0f / d;
    if (tid == 0) ld += logf(d);
    const float cr = pivc[cur][pr];
    float rw[8];
    *reinterpret_cast<float4*>(&rw[0]) = *reinterpret_cast<const float4*>(&pivr[cur][pc]);
    *reinterpret_cast<float4*>(&rw[4]) = *reinterpret_cast<const float4*>(&pivr[cur][pc + 4]);
    #pragma unroll
    for (int e = 0; e < 8; ++e) {
      float ge = fmaf(-inv_d * cr, rw[e], v[e]);         // general update
      if (pr == p)     ge = rw[e] * inv_d;               // pivot row
      if (pc + e == p) ge = (pr == p) ? -inv_d : cr * inv_d;  // pivot col/diag
      v[e] = ge;
    }
    if (p < BB - 1) {
      if (pr == p + 1) {
        #pragma unroll
        for (int e = 0; e < 8; ++e) pivr[nxt][pc + e] = v[e];
      }
      if (pc <= p + 1 && p + 1 < pc + 8) pivc[nxt][pr] = v[p + 1 - pc];
    }
    __syncthreads();
  }

  // store -P^{-1} for the update/deferred kernels (coalesced)
  float4 s0 = {v[0], v[1], v[2], v[3]};
  float4 s1 = {v[4], v[5], v[6], v[7]};
  *reinterpret_cast<float4*>(&Pb[pr * BB + pc]) = s0;
  *reinterpret_cast<float4*>(&Pb[pr * BB + pc + 4]) = s1;
  if (tid == 0) ldp[bs * KC + k] = ld;
}

// ---------------- Kernel 1b: trailing update of one non-J column slice ------
__global__ __launch_bounds__(512) void update_kernel(
    const float* __restrict__ covs, float* __restrict__ S,
    const float* __restrict__ Plbuf, int bs)
{
  const int k = blockIdx.x;
  const int si = blockIdx.y;
  const int t = si + (si >= bs ? 1 : 0);
  const int c0 = t * BB;
  const int j0 = bs * BB;
  const int tid = threadIdx.x;
  const float* src = ((bs == 0) ? covs : (const float*)S) + (size_t)k * DD * DD;
  float* dst = S + (size_t)k * DD * DD;

  __shared__ __align__(16) float Pl[BB][BB + 4];
  __shared__ __align__(16) float SJ[BB][BB + 4];
  __shared__ __align__(16) float Tl[BB][BB + 4];

  const float* Pb = Plbuf + (size_t)k * BB * BB;
  #pragma unroll
  for (int q = 0; q < 8; ++q) {
    int e = q * 512 + tid;
    int r = e >> 6, c = e & 63;
    Pl[r][c] = Pb[e];
    SJ[r][c] = src[(size_t)(j0 + r) * DD + c0 + c];
  }
  __syncthreads();

  // ---- T' = Pl * SJ  (thread: col c, 8 rows)
  {
    const int c = tid & 63;
    const int rg = (tid >> 6) * 8;
    float tv[8];
    #pragma unroll
    for (int r = 0; r < 8; ++r) tv[r] = 0.0f;
    for (int p = 0; p < BB; p += 4) {
      float s0 = SJ[p][c], s1 = SJ[p + 1][c], s2 = SJ[p + 2][c], s3 = SJ[p + 3][c];
      #pragma unroll
      for (int r = 0; r < 8; ++r) {
        float4 pv = *reinterpret_cast<const float4*>(&Pl[rg + r][p]);
        tv[r] = fmaf(pv.x, s0, fmaf(pv.y, s1, fmaf(pv.z, s2, fmaf(pv.w, s3, tv[r]))));
      }
    }
    #pragma unroll
    for (int r = 0; r < 8; ++r) Tl[rg + r][c] = tv[r];
  }
  __syncthreads();

  // ---- apply to this column slice (thread: row r, 32 cols)
  const int r = tid & 255;
  const int h = (tid >> 8) * 32;
  const bool inJ = (r >= j0) && (r < j0 + BB);  // wave-uniform
  if (inJ) {
    #pragma unroll
    for (int c = 0; c < 32; c += 4) {
      float4 tv4 = *reinterpret_cast<const float4*>(&Tl[r - j0][h + c]);
      float4 o = {-tv4.x, -tv4.y, -tv4.z, -tv4.w};
      *reinterpret_cast<float4*>(&dst[(size_t)r * DD + c0 + h + c]) = o;
    }
  } else {
    float Crow[BB];
    #pragma unroll
    for (int p = 0; p < BB; p += 4) {
      float4 cv = *reinterpret_cast<const float4*>(&src[(size_t)r * DD + j0 + p]);
      Crow[p] = cv.x; Crow[p + 1] = cv.y; Crow[p + 2] = cv.z; Crow[p + 3] = cv.w;
    }
    #pragma unroll
    for (int c = 0; c < 32; c += 4) {
      float4 acc = *reinterpret_cast<const float4*>(&src[(size_t)r * DD + c0 + h + c]);
      #pragma unroll
      for (int p = 0; p < BB; ++p) {
        float4 tv4 = *reinterpret_cast<const float4*>(&Tl[p][h + c]);
        acc.x = fmaf(Crow[p], tv4.x, acc.x);
        acc.y = fmaf(Crow[p], tv4.y, acc.y);
        acc.z = fmaf(Crow[p], tv4.z, acc.z);
        acc.w = fmaf(Crow[p], tv4.w, acc.w);
      }
      *reinterpret_cast<float4*>(&dst[(size_t)r * DD + c0 + h + c]) = acc;
    }
  }
}

// ---------------- Kernel 1c: wv_k = S_k * mu_k ; cA assembly -----------------
__global__ __launch_bounds__(256) void w_kernel(
    const float* __restrict__ S, const float* __restrict__ means,
    const float* __restrict__ counts, const int* __restrict__ n_points_p,
    const float* __restrict__ ldp, float* __restrict__ cA,
    float* __restrict__ wv)
{
  const int k = blockIdx.x;
  const int tid = threadIdx.x;
  if (tid == 0) {
    float denom = (float)(*n_points_p) + 1.0f;  // ALPHA = 1
    float ld = ldp[k] + ldp[KC + k] + ldp[2 * KC + k] + ldp[3 * KC + k];
    // D*log(2*pi) = 256 * 1.8378770664093453
    cA[k] = logf(counts[k] / denom) - 0.5f * (470.49652900079047f + ld);
  }
  const float* Sk = S + (size_t)k * DD * DD;
  __shared__ float mus[DD];
  mus[tid] = means[(size_t)k * DD + tid];
  __syncthreads();
  float a0 = 0.f, a1 = 0.f, a2 = 0.f, a3 = 0.f;
  for (int j = 0; j < DD; j += 4) {
    a0 = fmaf(Sk[(size_t)(j + 0) * DD + tid], mus[j + 0], a0);
    a1 = fmaf(Sk[(size_t)(j + 1) * DD + tid], mus[j + 1], a1);
    a2 = fmaf(Sk[(size_t)(j + 2) * DD + tid], mus[j + 2], a2);
    a3 = fmaf(Sk[(size_t)(j + 3) * DD + tid], mus[j + 3], a3);
  }
  wv[(size_t)k * DD + tid] = (a0 + a1) + (a2 + a3);
}

// ---------------- Kernel 2: quad via mean-folded GEMM ------------------------
// dev^T S dev = sum_j (x_j - mu_j) * ((X*S)_nj - wv_j)   (S symmetric).
// 8n x 8j register tile, ONE cluster at a time: per il step 4 ds_read_b128
// feed 64 FMAs (0.25 LDS-floats/FMA). 64 accumulators + ~50 temps fit the
// 128-VGPR cap with NO spill (r5/r6's paired 128-acc tile spilled ~60
// floats/thread -> 125 MB scratch WRITE; allocator refuses >128 VGPRs).
// KG=4 clusters per block (r2's faster 1024-block grid). S streamed in
// CH=8-row chunks, register-prefetched. LDS = 64+8+2+1 = 75 KB -> 2 blocks/CU.
__global__ __launch_bounds__(256) void quad_kernel(
    const float* __restrict__ X, const float* __restrict__ means,
    const float* __restrict__ S, const float* __restrict__ cA,
    const float* __restrict__ wv, float* __restrict__ lp)
{
  __shared__ __align__(16) float XT[DD][NT];   // (i,r) at XT[i][r ^ (((i>>2)&15)<<2)]
  __shared__ __align__(16) float Pl[CH * DD];  // S chunk (2048 floats); qred alias
  __shared__ __align__(16) float muw[2][DD];   // mu_k, wv_k
  __shared__ __align__(16) float lpb[KG][NT];  // results, flushed at end

  const int tid = threadIdx.x;
  const int n0 = blockIdx.x * NT;
  const int k0 = blockIdx.y * KG;

  // stage X tile transposed + swizzled (once per block)
  #pragma unroll
  for (int q = 0; q < 16; ++q) {
    int f = q * 1024 + tid * 4;
    int r = f >> 8;
    int c = f & 255;
    float4 xv = *reinterpret_cast<const float4*>(X + (size_t)(n0 + r) * DD + c);
    int rs = r ^ (((c >> 2) & 15) << 2);
    XT[c + 0][rs] = xv.x;
    XT[c + 1][rs] = xv.y;
    XT[c + 2][rs] = xv.z;
    XT[c + 3][rs] = xv.w;
  }

  const int tn = tid & 7;    // n sub-tile: rows tn*8 .. +7
  const int tj = tid >> 3;   // j sub-tile: cols tj*8 .. +7
  const int f0 = tid * 4;
  const int f1 = 1024 + tid * 4;

  #pragma unroll 1
  for (int kk = 0; kk < KG; ++kk) {
    const int k = k0 + kk;
    const float* Sk = S + (size_t)k * DD * DD;

    __syncthreads();  // prev k's qred/muw readers done; XT staged (kk==0)
    muw[0][tid] = means[(size_t)k * DD + tid];
    muw[1][tid] = wv[(size_t)k * DD + tid];

    // prologue: chunk 0 -> registers
    float4 pre0 = *reinterpret_cast<const float4*>(Sk + f0);
    float4 pre1 = *reinterpret_cast<const float4*>(Sk + f1);

    float y[8][8];
    #pragma unroll
    for (int a = 0; a < 8; ++a)
      #pragma unroll
      for (int b = 0; b < 8; ++b) y[a][b] = 0.0f;

    #pragma unroll 1
    for (int ct = 0; ct < NCH; ++ct) {
      __syncthreads();  // Pl free (prev chunk consumed); muw/XT visible
      *reinterpret_cast<float4*>(&Pl[f0]) = pre0;
      *reinterpret_cast<float4*>(&Pl[f1]) = pre1;
      if (ct < NCH - 1) {  // next chunk's loads stay in flight across compute
        const float* srcp = Sk + (size_t)(ct + 1) * CH * DD;
        pre0 = *reinterpret_cast<const float4*>(srcp + f0);
        pre1 = *reinterpret_cast<const float4*>(srcp + f1);
      }
      __syncthreads();  // Pl ready

      #pragma unroll
      for (int il = 0; il < CH; ++il) {
        const int i = ct * CH + il;
        const int sw = ((i >> 2) & 15) << 2;
        float xv[8], pv[8];
        *reinterpret_cast<float4*>(&xv[0]) =
            *reinterpret_cast<const float4*>(&XT[i][(tn * 8) ^ sw]);
        *reinterpret_cast<float4*>(&xv[4]) =
            *reinterpret_cast<const float4*>(&XT[i][(tn * 8 + 4) ^ sw]);
        *reinterpret_cast<float4*>(&pv[0]) =
            *reinterpret_cast<const float4*>(&Pl[il * DD + tj * 8]);
        *reinterpret_cast<float4*>(&pv[4]) =
            *reinterpret_cast<const float4*>(&Pl[il * DD + tj * 8 + 4]);
        #pragma unroll
        for (int a = 0; a < 8; ++a)
          #pragma unroll
          for (int b = 0; b < 8; ++b)
            y[a][b] = fmaf(xv[a], pv[b], y[a][b]);
      }
    }

    // epilogue: q'[n] = sum_j (x[n,j]-mu_j) * (y[n,j]-wv_j), partial over 8 j
    float s[8];
    #pragma unroll
    for (int a = 0; a < 8; ++a) s[a] = 0.0f;
    #pragma unroll
    for (int b = 0; b < 8; ++b) {
      const int j = tj * 8 + b;
      const int swj = ((j >> 2) & 15) << 2;
      float dv[8];
      *reinterpret_cast<float4*>(&dv[0]) =
          *reinterpret_cast<const float4*>(&XT[j][(tn * 8) ^ swj]);
      *reinterpret_cast<float4*>(&dv[4]) =
          *reinterpret_cast<const float4*>(&XT[j][(tn * 8 + 4) ^ swj]);
      const float mj = muw[0][j];
      const float wj = muw[1][j];
      #pragma unroll
      for (int a = 0; a < 8; ++a)
        s[a] = fmaf(dv[a] - mj, y[a][b] - wj, s[a]);
    }

    float* qred = &Pl[0];  // 2048 floats; Pl dead until next k
    __syncthreads();       // all threads' compute reads of Pl done
    *reinterpret_cast<float4*>(&qred[tj * 64 + tn * 8]) =
        *reinterpret_cast<const float4*>(&s[0]);
    *reinterpret_cast<float4*>(&qred[tj * 64 + tn * 8 + 4]) =
        *reinterpret_cast<const float4*>(&s[4]);
    __syncthreads();
    if (tid < 64) {
      float qa = 0.f, qb = 0.f, qc = 0.f, qd = 0.f;
      #pragma unroll
      for (int t = 0; t < 32; t += 4) {
        qa += qred[(t + 0) * 64 + tid];
        qb += qred[(t + 1) * 64 + tid];
        qc += qred[(t + 2) * 64 + tid];
        qd += qred[(t + 3) * 64 + tid];
      }
      // q' = dev^T S dev = -quad  ->  lp = cA + 0.5*q'
      lpb[kk][tid] = fmaf(0.5f, (qa + qb) + (qc + qd), cA[k]);
    }
  }

  // lp flush: one float4 of 4 k-values per point row
  __syncthreads();
  if (tid < 64) {
    float4 o = {lpb[0][tid], lpb[1][tid], lpb[2][tid], lpb[3][tid]};
    *reinterpret_cast<float4*>(&lp[(size_t)(n0 + tid) * KC + k0]) = o;
  }
}

// ---------------- Kernel 3: row softmax over K+1 = 65 entries -----------------
__global__ __launch_bounds__(64) void softmax_kernel(
    const float* __restrict__ lp, const int* __restrict__ n_points_p,
    float* __restrict__ out)
{
  const int n = blockIdx.x;
  const int l = threadIdx.x;
  const float denom = (float)(*n_points_p) + 1.0f;
  const float log_new = -logf(denom);  // log(ALPHA/denom), ALPHA=1

  float v = lp[(size_t)n * KC + l];
  float m = v;
  #pragma unroll
  for (int off = 32; off > 0; off >>= 1) m = fmaxf(m, __shfl_xor(m, off, 64));
  m = fmaxf(m, log_new);

  float e = expf(v - m);
  float s = e;
  #pragma unroll
  for (int off = 32; off > 0; off >>= 1) s += __shfl_xor(s, off, 64);
  float enew = expf(log_new - m);
  s += enew;

  out[(size_t)n * (KC + 1) + l] = e / s;
  if (l == 0) out[(size_t)n * (KC + 1) + KC] = enew / s;
}

extern "C" void kernel_launch(void* const* d_in, const int* in_sizes, int n_in,
                              void* d_out, int out_size, void* d_ws, size_t ws_size,
                              hipStream_t stream)
{
  const float* x       = (const float*)d_in[0];  // [N, D]
  const float* means   = (const float*)d_in[1];  // [K, D]
  const float* covs    = (const float*)d_in[2];  // [K, D, D]
  const float* counts  = (const float*)d_in[3];  // [K]
  const int*   n_points = (const int*)d_in[4];   // scalar

  float* S   = (float*)d_ws;                      // K*D*D
  float* cA  = S + (size_t)KC * DD * DD;          // K
  float* ldp = cA + KC;                           // 4*K
  float* lp  = ldp + 4 * KC;                      // N*K
  float* Plbuf = lp;  // alias: Plbuf (K*64*64 = N*K floats) used only during
                      // sweep; lp written only by quad afterwards.
  float* out = (float*)d_out;                     // [N, K+1]
  // wv = S_k*mu_k staged in the out buffer (64KB of 1MB); quad reads it before
  // softmax overwrites out — stream-ordered, safe.
  float* wv = out;

  for (int bs = 0; bs < 4; ++bs) {
    pivot_kernel<<<dim3(KC, 5), 512, 0, stream>>>(covs, S, Plbuf, ldp, bs);
    update_kernel<<<dim3(KC, 3), 512, 0, stream>>>(covs, S, Plbuf, bs);
  }
  pivot_kernel<<<dim3(KC, 5), 512, 0, stream>>>(covs, S, Plbuf, ldp, 4);
  w_kernel<<<KC, 256, 0, stream>>>(S, means, counts, n_points, ldp, cA, wv);
  quad_kernel<<<dim3(NPTS / NT, KC / KG), 256, 0, stream>>>(x, means, S, cA, wv, lp);
  softmax_kernel<<<NPTS, 64, 0, stream>>>(lp, n_points, out);
}